// Round 8
// baseline (542.392 us; speedup 1.0000x reference)
//
#include <hip/hip_runtime.h>
#include <hip/hip_bf16.h>

// Problem constants
#define Bn 2
#define INCH 256
#define OUTCH 128
#define Hs 96
#define Ws 96
#define HW (Hs*Ws)          // 9216
#define N9 9

typedef __attribute__((ext_vector_type(8))) short bf16x8;
typedef __attribute__((ext_vector_type(4))) float f32x4;

static __device__ inline ushort bfbits(float v) {
    __hip_bfloat16 h = __float2bfloat16(v);
    return *reinterpret_cast<ushort*>(&h);
}
static __device__ inline float bf2f(ushort u) {
    __hip_bfloat16 h = *reinterpret_cast<__hip_bfloat16*>(&u);
    return __bfloat162float(h);
}
static __device__ inline uint packu(ushort lo, ushort hi) {
    return (uint)lo | ((uint)hi << 16);
}
// NHWC packed value: uint = hi_bits | (lo_bits<<16); reconstruct f32 halves:
static __device__ inline float rchi(uint u) { return __uint_as_float(u << 16); }
static __device__ inline float rclo(uint u) { return __uint_as_float(u & 0xffff0000u); }

// ---------------- bilinear 2x upsample, align_corners=True ----------------
__global__ void up2_kernel(const float* __restrict__ in, float* __restrict__ out) {
    int idx = blockIdx.x * blockDim.x + threadIdx.x;
    const int total = Bn * INCH * HW;
    if (idx >= total) return;
    int xo = idx % Ws;
    int yo = (idx / Ws) % Hs;
    int bc = idx / HW;
    const float s = 47.0f / 95.0f;
    float yf = yo * s, xf = xo * s;
    int y0 = (int)floorf(yf); int y1 = min(y0 + 1, 47);
    int x0 = (int)floorf(xf); int x1 = min(x0 + 1, 47);
    float wy = yf - (float)y0, wx = xf - (float)x0;
    const float* p = in + (size_t)bc * 2304;
    float r0 = p[y0*48 + x0] * (1.f - wy) + p[y1*48 + x0] * wy;
    float r1 = p[y0*48 + x1] * (1.f - wy) + p[y1*48 + x1] * wy;
    out[idx] = r0 * (1.f - wx) + r1 * wx;
}

// ---------------- NCHW f32 -> NHWC packed bf16 (hi|lo<<16) transpose ----------------
template<int C>
__global__ void t_nhwc_kernel(const float* __restrict__ in, uint* __restrict__ out) {
    __shared__ float t[32][33];
    constexpr int PB = HW / 32;          // 288
    int blk = blockIdx.x;
    int p0 = (blk % PB) * 32;
    int c0 = ((blk / PB) % (C / 32)) * 32;
    int b = blk / (PB * (C / 32));
    int tp = threadIdx.x & 31, tg = threadIdx.x >> 5;   // tg 0..7
    #pragma unroll
    for (int r = 0; r < 4; r++) {
        int c = c0 + tg + r * 8;
        t[tg + r * 8][tp] = in[((size_t)b * C + c) * HW + p0 + tp];
    }
    __syncthreads();
    #pragma unroll
    for (int r = 0; r < 4; r++) {
        int p = p0 + tg + r * 8;
        float v = t[tp][tg + r * 8];
        ushort h = bfbits(v);
        ushort l = bfbits(v - bf2f(h));
        out[((size_t)b * HW + p) * C + c0 + tp] = packu(h, l);
    }
}

// ---------------- copy x1 into channels [128..256) of concat buffer ----------------
__global__ void copy_x1_kernel(const float* __restrict__ x1, float* __restrict__ xcat) {
    int idx = blockIdx.x * blockDim.x + threadIdx.x;
    const int total = Bn * OUTCH * HW;
    if (idx >= total) return;
    int b = idx / (OUTCH * HW);
    int r = idx % (OUTCH * HW);
    xcat[((size_t)b * INCH + OUTCH) * HW + r] = x1[idx];
}

// ---------------- offset conv (3x3, pad=1, COUT=18) fp32, channel-split partials -------
template<int CIN, int SPLIT>
__global__ void offconv_kernel(const float* __restrict__ in, const float* __restrict__ w,
                               float* __restrict__ part) {
    constexpr int CS = CIN / SPLIT;
    constexpr int BPS = Bn * HW / 256;   // 72
    int s = blockIdx.x / BPS;
    int p = (blockIdx.x % BPS) * 256 + threadIdx.x;
    int b = p / HW; int pin = p % HW;
    int i = pin / Ws, j = pin % Ws;
    const float* ib = in + ((size_t)b * CIN + s * CS) * HW;
    const float* wb = w + (size_t)s * CS * N9;
    float acc[18];
    #pragma unroll
    for (int o = 0; o < 18; o++) acc[o] = 0.f;
    for (int c = 0; c < CS; c++) {
        float v[9];
        #pragma unroll
        for (int n = 0; n < 9; n++) {
            int rr = i + n / 3 - 1, cc = j + n % 3 - 1;
            v[n] = (rr >= 0 && rr < Hs && cc >= 0 && cc < Ws) ? ib[(size_t)c * HW + rr * Ws + cc] : 0.f;
        }
        const float* wc = wb + (size_t)c * N9;
        #pragma unroll
        for (int o = 0; o < 18; o++) {
            #pragma unroll
            for (int n = 0; n < 9; n++) acc[o] += wc[(size_t)o * CIN * N9 + n] * v[n];
        }
    }
    #pragma unroll
    for (int o = 0; o < 18; o++)
        part[(((size_t)s * Bn + b) * 18 + o) * HW + pin] = acc[o];
}

template<int SPLIT>
__global__ void offreduce_kernel(const float* __restrict__ part, const float* __restrict__ bias,
                                 float* __restrict__ off) {
    int idx = blockIdx.x * blockDim.x + threadIdx.x;
    const int total = Bn * 18 * HW;
    if (idx >= total) return;
    int pin = idx % HW;
    int o = (idx / HW) % 18;
    int b = idx / (18 * HW);
    float a = bias[o];
    #pragma unroll
    for (int s = 0; s < SPLIT; s++) a += part[(((size_t)s * Bn + b) * 18 + o) * HW + pin];
    off[((size_t)b * 18 + o) * HW + pin] = a;
}

// ------ weight prep: [oc][c][3][3] fp32 -> bf16 hi[k/32][128][32] ++ lo; k = n*CIN + c ------
template<int CIN>
__global__ void wprep_big_kernel(const float* __restrict__ cw, ushort* __restrict__ wp) {
    int e = blockIdx.x * 256 + threadIdx.x;
    if (e >= CIN * 9 * 128) return;
    int kl = e & 31, oc = (e >> 5) & 127, k32 = e >> 12;
    int k = k32 * 32 + kl;
    int n = k / CIN, c = k & (CIN - 1);
    float v = cw[((size_t)oc * CIN + c) * 9 + n];
    ushort h = bfbits(v);
    wp[e] = h;
    wp[e + CIN * 9 * 128] = bfbits(v - bf2f(h));
}

// ---------------- sampling params: indices + bilinear weights ----------------
__global__ void mkparams_kernel(const float* __restrict__ off, int4* __restrict__ pidx,
                                float4* __restrict__ pw) {
    int e = blockIdx.x * blockDim.x + threadIdx.x;
    const int total = Bn * HW * N9;
    if (e >= total) return;
    int n = e % N9;
    int p = e / N9;
    int j = p % Ws;
    int i = (p / Ws) % Hs;
    int b = p / HW;
    float ox = off[((size_t)b * 18 + n) * HW + i * Ws + j];
    float oy = off[((size_t)b * 18 + 9 + n) * HW + i * Ws + j];
    float px = ox + (float)(n / 3 - 1) + (float)(i + 1);
    float py = oy + (float)(n % 3 - 1) + (float)(j + 1);
    float fx = floorf(px), fy = floorf(py);
    float x_lt = fminf(fmaxf(fx,       0.f), 95.f);
    float x_rb = fminf(fmaxf(fx + 1.f, 0.f), 95.f);
    float y_lt = fminf(fmaxf(fy,       0.f), 95.f);
    float y_rb = fminf(fmaxf(fy + 1.f, 0.f), 95.f);
    float pxc  = fminf(fmaxf(px, 0.f), 95.f);
    float pyc  = fminf(fmaxf(py, 0.f), 95.f);
    float g_lt = (1.f + (x_lt - pxc)) * (1.f + (y_lt - pyc));
    float g_rb = (1.f - (x_rb - pxc)) * (1.f - (y_rb - pyc));
    float g_lb = (1.f + (x_lt - pxc)) * (1.f - (y_rb - pyc));
    float g_rt = (1.f - (x_rb - pxc)) * (1.f + (y_lt - pyc));
    int ilt = (int)x_lt * Ws + (int)y_lt;
    int irb = (int)x_rb * Ws + (int)y_rb;
    int ilb = (int)x_lt * Ws + (int)y_rb;
    int irt = (int)x_rb * Ws + (int)y_lt;
    pidx[e] = make_int4(ilt, irb, ilb, irt);
    pw[e]   = make_float4(g_lt, g_rb, g_lb, g_rt);
}

// ---------------- MFMA GEMM, NHWC fill: 16 px x 128 oc per block, split-K x2 ----------------
// Input is NHWC packed uint (hi|lo<<16). K-order: k = n*CIN + c -> each 64-K step is one tap n,
// 64 channels: fill = 4 coalesced dwordx4 loads/thread (deform) or 1 (conv).
// 4 waves; wave w: oc slice [32w,32w+32). A = weights (m=oc), B = patch (n=px).
// D: col(lane&15)=px -> coalesced stores; row((lane>>4)*4+r)=oc.
template<int CIN, bool DEFORM, bool SPLIT3>
__global__ void mgemm_big_kernel(const uint* __restrict__ xT, const ushort* __restrict__ wp,
                                 const int4* __restrict__ pidx, const float4* __restrict__ pw,
                                 float* __restrict__ p0, float* __restrict__ p1) {
    constexpr int KS = CIN * 9 / 2;
    constexpr int NSTEP = KS / 64;
    constexpr int TILES = Bn * HW / 16;   // 1152
    __shared__ ushort Ah[16][80];         // [px][64k + pad] bf16 hi, col-swizzled
    __shared__ ushort Al[16][80];         // lo
    __shared__ int4  sidx[144];
    __shared__ float4 ssw[144];

    int tid = threadIdx.x;
    // XCD-aware swizzle: 2304 blocks, 8 XCDs, 288 contiguous per XCD
    int bid = blockIdx.x;
    int swz = (bid & 7) * 288 + (bid >> 3);
    int s = swz / TILES;
    int t = swz % TILES;
    int p0x = t * 16;
    int b = p0x / HW;
    int pin = p0x % HW;
    int irow = pin / Ws, j0 = pin % Ws;

    if constexpr (DEFORM) {
        if (tid < 144) {
            sidx[tid] = pidx[(size_t)p0x * N9 + tid];
            ssw[tid]  = pw[(size_t)p0x * N9 + tid];
        }
    }
    const uint* xbT = xT + (size_t)b * HW * CIN;
    const ushort* wlo = wp + (size_t)CIN * 9 * 128;
    int w = tid >> 6, lane = tid & 63;
    int lg = lane >> 4, l15 = lane & 15;
    int fpx = tid & 15, fc4 = tid >> 4;   // fill: px, channel-quad 0..15

    f32x4 acc[2];
    acc[0] = (f32x4){0.f, 0.f, 0.f, 0.f};
    acc[1] = (f32x4){0.f, 0.f, 0.f, 0.f};
    int bswz = (l15 >> 2) << 3;           // read-side col swizzle (ushorts)

    for (int ks = 0; ks < NSTEP; ks++) {
        int k0 = s * KS + ks * 64;
        int n = k0 / CIN;                 // tap (constexpr pow2 div)
        int cc = (k0 & (CIN - 1)) + fc4 * 4;
        __syncthreads();
        // ---- fill: 16px x 64ch, NHWC coalesced ----
        ushort h[4], l[4];
        if constexpr (DEFORM) {
            int4 i4 = sidx[fpx * 9 + n];
            float4 w4 = ssw[fpx * 9 + n];
            uint qa[4], qb[4], qc[4], qd[4];
            *(uint4*)qa = *(const uint4*)&xbT[(size_t)i4.x * CIN + cc];
            *(uint4*)qb = *(const uint4*)&xbT[(size_t)i4.y * CIN + cc];
            *(uint4*)qc = *(const uint4*)&xbT[(size_t)i4.z * CIN + cc];
            *(uint4*)qd = *(const uint4*)&xbT[(size_t)i4.w * CIN + cc];
            #pragma unroll
            for (int j = 0; j < 4; j++) {
                float v = w4.x * (rchi(qa[j]) + rclo(qa[j]))
                        + w4.y * (rchi(qb[j]) + rclo(qb[j]))
                        + w4.z * (rchi(qc[j]) + rclo(qc[j]))
                        + w4.w * (rchi(qd[j]) + rclo(qd[j]));
                h[j] = bfbits(v);
                if constexpr (SPLIT3) l[j] = bfbits(v - bf2f(h[j]));
            }
        } else {
            int dy = n / 3 - 1, dx = n % 3 - 1;
            int rr = irow + dy, ccol = j0 + fpx + dx;
            uint qa[4] = {0u, 0u, 0u, 0u};
            if (rr >= 0 && rr < Hs && ccol >= 0 && ccol < Ws)
                *(uint4*)qa = *(const uint4*)&xbT[(size_t)(rr * Ws + ccol) * CIN + cc];
            #pragma unroll
            for (int j = 0; j < 4; j++) {
                h[j] = (ushort)(qa[j] & 0xffffu);
                if constexpr (SPLIT3) l[j] = (ushort)(qa[j] >> 16);
            }
        }
        int col = (fc4 * 4) ^ ((fpx >> 2) << 3);   // write-side swizzle (ushorts, 8B-aligned)
        uint2 wh; wh.x = packu(h[0], h[1]); wh.y = packu(h[2], h[3]);
        *(uint2*)&Ah[fpx][col] = wh;
        if constexpr (SPLIT3) {
            uint2 wl; wl.x = packu(l[0], l[1]); wl.y = packu(l[2], l[3]);
            *(uint2*)&Al[fpx][col] = wl;
        }
        __syncthreads();
        // ---- MAC: 2 K-halves; SPLIT3 -> ah*bh + ah*bl + al*bh ----
        #pragma unroll
        for (int kk = 0; kk < 2; kk++) {
            const ushort* wpk = wp + ((size_t)(k0 / 32 + kk) * 128) * 32;
            int bcol = (kk * 32 + lg * 8) ^ bswz;
            bf16x8 a0h = *(const bf16x8*)&wpk[(32 * w + l15) * 32 + lg * 8];
            bf16x8 a1h = *(const bf16x8*)&wpk[(32 * w + 16 + l15) * 32 + lg * 8];
            bf16x8 b0h = *(const bf16x8*)&Ah[l15][bcol];
            acc[0] = __builtin_amdgcn_mfma_f32_16x16x32_bf16(a0h, b0h, acc[0], 0, 0, 0);
            acc[1] = __builtin_amdgcn_mfma_f32_16x16x32_bf16(a1h, b0h, acc[1], 0, 0, 0);
            if constexpr (SPLIT3) {
                const ushort* wpl = wlo + ((size_t)(k0 / 32 + kk) * 128) * 32;
                bf16x8 a0l = *(const bf16x8*)&wpl[(32 * w + l15) * 32 + lg * 8];
                bf16x8 a1l = *(const bf16x8*)&wpl[(32 * w + 16 + l15) * 32 + lg * 8];
                bf16x8 b0l = *(const bf16x8*)&Al[l15][bcol];
                acc[0] = __builtin_amdgcn_mfma_f32_16x16x32_bf16(a0h, b0l, acc[0], 0, 0, 0);
                acc[0] = __builtin_amdgcn_mfma_f32_16x16x32_bf16(a0l, b0h, acc[0], 0, 0, 0);
                acc[1] = __builtin_amdgcn_mfma_f32_16x16x32_bf16(a1h, b0l, acc[1], 0, 0, 0);
                acc[1] = __builtin_amdgcn_mfma_f32_16x16x32_bf16(a1l, b0h, acc[1], 0, 0, 0);
            }
        }
    }
    float* pout = s ? p1 : p0;
    #pragma unroll
    for (int mf = 0; mf < 2; mf++) {
        int oc = 32 * w + 16 * mf + lg * 4;
        #pragma unroll
        for (int r = 0; r < 4; r++)
            pout[((size_t)b * OUTCH + oc + r) * HW + pin + l15] = acc[mf][r];
    }
}

// ---------------- combine split-K partials + bias + ReLU -> xcat[:, 0:128] ----------------
__global__ void combine_halve_kernel(const float* __restrict__ p0, const float* __restrict__ p1,
                                     const float* __restrict__ bias, float* __restrict__ xcat) {
    int idx = blockIdx.x * blockDim.x + threadIdx.x;
    const int total = Bn * OUTCH * HW;
    if (idx >= total) return;
    int b = idx / (OUTCH * HW);
    int o = (idx / HW) % OUTCH;
    int pin = idx % HW;
    float v = p0[idx] + p1[idx] + bias[o];
    xcat[((size_t)b * INCH + o) * HW + pin] = fmaxf(v, 0.f);
}

// ---------------- training-mode BN statistics over (p0+p1) ----------------
__global__ void bnstats_kernel(const float* __restrict__ p0, const float* __restrict__ p1,
                               float* __restrict__ mv) {
    int o = blockIdx.x;
    int tid = threadIdx.x;
    float s = 0.f, sq = 0.f;
    for (int k = tid; k < Bn * HW; k += 256) {
        int b = k / HW, p = k % HW;
        size_t idx = ((size_t)b * OUTCH + o) * HW + p;
        float v = p0[idx] + p1[idx];
        s += v; sq += v * v;
    }
    __shared__ float rs[256], rq[256];
    rs[tid] = s; rq[tid] = sq;
    __syncthreads();
    for (int st = 128; st > 0; st >>= 1) {
        if (tid < st) { rs[tid] += rs[tid + st]; rq[tid] += rq[tid + st]; }
        __syncthreads();
    }
    if (tid == 0) {
        float m = rs[0] / (float)(Bn * HW);
        mv[o] = m;
        mv[OUTCH + o] = rq[0] / (float)(Bn * HW) - m * m;
    }
}

// ---------------- BN apply + ReLU over (p0+p1) ----------------
__global__ void bnapply_kernel(const float* __restrict__ p0, const float* __restrict__ p1,
                               const float* __restrict__ mv,
                               const float* __restrict__ g, const float* __restrict__ be,
                               float* __restrict__ y) {
    int idx = blockIdx.x * blockDim.x + threadIdx.x;
    const int total = Bn * OUTCH * HW;
    if (idx >= total) return;
    int o = (idx / HW) % OUTCH;
    float m = mv[o], v = mv[OUTCH + o];
    float x = p0[idx] + p1[idx];
    float r = (x - m) / sqrtf(v + 1e-5f) * g[o] + be[o];
    y[idx] = fmaxf(r, 0.f);
}

extern "C" void kernel_launch(void* const* d_in, const int* in_sizes, int n_in,
                              void* d_out, int out_size, void* d_ws, size_t ws_size,
                              hipStream_t stream) {
    const float* x1   = (const float*)d_in[0];
    const float* x2   = (const float*)d_in[1];
    const float* chW  = (const float*)d_in[2];
    const float* chB  = (const float*)d_in[3];
    const float* p1W  = (const float*)d_in[4];
    const float* p1B  = (const float*)d_in[5];
    const float* c1W  = (const float*)d_in[6];
    const float* bn1g = (const float*)d_in[7];
    const float* bn1b = (const float*)d_in[8];
    const float* p2W  = (const float*)d_in[9];
    const float* p2B  = (const float*)d_in[10];
    const float* c2W  = (const float*)d_in[11];
    const float* bn2g = (const float*)d_in[12];
    const float* bn2b = (const float*)d_in[13];
    float* out = (float*)d_out;

    float* ws = (float*)d_ws;
    // Regions (floats): A=[0,4718592) B=[4718592,9437184) C=[9437184,11796480) D=[11796480,14155776)
    // Phase H: x2u@A -> x2uT@C∪D; cwThb@B[0..294912); mgemm: p0h@A[0), p1h@A[2359296);
    //          combine -> xcat@B; copy_x1 -> xcat@B   (x2u dead after transpose, cwThb dead after mgemm)
    // Stage 1: part@A[0..2654208), offb@A[2654208), pidx@A[2985984), pw4@A[3649536),
    //          cwTb1@A[4313088..4608000); xcat@B -> xcatT@C∪D; mgemm1: p0d@B[0), p1d@B[2359296);
    //          bnapply -> y1@A[0..2359296)
    // Stage 2: part@B[0..2654208), offb@B[+2654208), pidx@B[+2985984), pw4@B[+3649536),
    //          cwTb2@B[+4313088); y1@A -> y1T@C; mgemm2: p0d@A[0), p1d@A[2359296) -> out
    float* x2u   = ws;
    uint*  x2uT  = (uint*)(ws + 9437184);
    ushort* cwThb = (ushort*)(ws + 4718592);
    float* p0h   = ws;
    float* p1h   = ws + 2359296;
    float* xcat  = ws + 4718592;

    float* part1 = ws;
    float* offb1 = ws + 2654208;
    int4*  pidx1 = (int4*)(ws + 2985984);
    float4* pw41 = (float4*)(ws + 3649536);
    ushort* cwTb1 = (ushort*)(ws + 4313088);
    uint*  xcatT = (uint*)(ws + 9437184);
    float* p0d1  = ws + 4718592;
    float* p1d1  = ws + 4718592 + 2359296;
    float* y1    = ws;

    float* part2 = ws + 4718592;
    float* offb2 = ws + 4718592 + 2654208;
    int4*  pidx2 = (int4*)(ws + 4718592 + 2985984);
    float4* pw42 = (float4*)(ws + 4718592 + 3649536);
    ushort* cwTb2 = (ushort*)(ws + 4718592 + 4313088);
    uint*  y1T   = (uint*)(ws + 9437184);
    float* p0d2  = ws;
    float* p1d2  = ws + 2359296;
    float* mv    = ws + 14155776;

    constexpr int BIG_GRID = 2 * Bn * HW / 16;          // 2304
    constexpr int T256_GRID = (HW/32) * (INCH/32) * Bn; // 4608
    constexpr int T128_GRID = (HW/32) * (OUTCH/32) * Bn;// 2304

    // ---- halve-channel conv ----
    up2_kernel<<<(Bn*INCH*HW + 255) / 256, 256, 0, stream>>>(x2, x2u);
    t_nhwc_kernel<INCH><<<T256_GRID, 256, 0, stream>>>(x2u, x2uT);
    wprep_big_kernel<INCH><<<(INCH*9*128 + 255) / 256, 256, 0, stream>>>(chW, cwThb);
    mgemm_big_kernel<INCH, false, true><<<BIG_GRID, 256, 0, stream>>>(x2uT, cwThb, nullptr, nullptr, p0h, p1h);
    combine_halve_kernel<<<(Bn*OUTCH*HW + 255) / 256, 256, 0, stream>>>(p0h, p1h, chB, xcat);
    copy_x1_kernel<<<(Bn*OUTCH*HW + 255) / 256, 256, 0, stream>>>(x1, xcat);

    // ---- stage 1 (offsets fp32; deform GEMM split-precision MFMA, NHWC fill) ----
    offconv_kernel<INCH, 8><<<8 * (Bn*HW/256), 256, 0, stream>>>(xcat, p1W, part1);
    offreduce_kernel<8><<<(Bn*18*HW + 255) / 256, 256, 0, stream>>>(part1, p1B, offb1);
    mkparams_kernel<<<(Bn*HW*N9 + 255) / 256, 256, 0, stream>>>(offb1, pidx1, pw41);
    wprep_big_kernel<INCH><<<(INCH*9*128 + 255) / 256, 256, 0, stream>>>(c1W, cwTb1);
    t_nhwc_kernel<INCH><<<T256_GRID, 256, 0, stream>>>(xcat, xcatT);
    mgemm_big_kernel<INCH, true, true><<<BIG_GRID, 256, 0, stream>>>(xcatT, cwTb1, pidx1, pw41, p0d1, p1d1);
    bnstats_kernel<<<OUTCH, 256, 0, stream>>>(p0d1, p1d1, mv);
    bnapply_kernel<<<(Bn*OUTCH*HW + 255) / 256, 256, 0, stream>>>(p0d1, p1d1, mv, bn1g, bn1b, y1);

    // ---- stage 2 (final output: plain bf16 MFMA) ----
    offconv_kernel<OUTCH, 8><<<8 * (Bn*HW/256), 256, 0, stream>>>(y1, p2W, part2);
    offreduce_kernel<8><<<(Bn*18*HW + 255) / 256, 256, 0, stream>>>(part2, p2B, offb2);
    mkparams_kernel<<<(Bn*HW*N9 + 255) / 256, 256, 0, stream>>>(offb2, pidx2, pw42);
    wprep_big_kernel<OUTCH><<<(OUTCH*9*128 + 255) / 256, 256, 0, stream>>>(c2W, cwTb2);
    t_nhwc_kernel<OUTCH><<<T128_GRID, 256, 0, stream>>>(y1, y1T);
    mgemm_big_kernel<OUTCH, true, false><<<BIG_GRID, 256, 0, stream>>>(y1T, cwTb2, pidx2, pw42, p0d2, p1d2);
    bnstats_kernel<<<OUTCH, 256, 0, stream>>>(p0d2, p1d2, mv);
    bnapply_kernel<<<(Bn*OUTCH*HW + 255) / 256, 256, 0, stream>>>(p0d2, p1d2, mv, bn2g, bn2b, out);
}

// Round 9
// 459.727 us; speedup vs baseline: 1.1798x; 1.1798x over previous
//
#include <hip/hip_runtime.h>
#include <hip/hip_bf16.h>

// Problem constants
#define Bn 2
#define INCH 256
#define OUTCH 128
#define Hs 96
#define Ws 96
#define HW (Hs*Ws)          // 9216
#define N9 9

typedef __attribute__((ext_vector_type(8))) short bf16x8;
typedef __attribute__((ext_vector_type(4))) float f32x4;

static __device__ inline ushort bfbits(float v) {
    __hip_bfloat16 h = __float2bfloat16(v);
    return *reinterpret_cast<ushort*>(&h);
}
static __device__ inline float bf2f(ushort u) {
    __hip_bfloat16 h = *reinterpret_cast<__hip_bfloat16*>(&u);
    return __bfloat162float(h);
}
static __device__ inline uint packu(ushort lo, ushort hi) {
    return (uint)lo | ((uint)hi << 16);
}
// NHWC packed value: uint = hi_bits | (lo_bits<<16); reconstruct f32 halves:
static __device__ inline float rchi(uint u) { return __uint_as_float(u << 16); }
static __device__ inline float rclo(uint u) { return __uint_as_float(u & 0xffff0000u); }

// ---------------- bilinear 2x upsample, align_corners=True ----------------
__global__ void up2_kernel(const float* __restrict__ in, float* __restrict__ out) {
    int idx = blockIdx.x * blockDim.x + threadIdx.x;
    const int total = Bn * INCH * HW;
    if (idx >= total) return;
    int xo = idx % Ws;
    int yo = (idx / Ws) % Hs;
    int bc = idx / HW;
    const float s = 47.0f / 95.0f;
    float yf = yo * s, xf = xo * s;
    int y0 = (int)floorf(yf); int y1 = min(y0 + 1, 47);
    int x0 = (int)floorf(xf); int x1 = min(x0 + 1, 47);
    float wy = yf - (float)y0, wx = xf - (float)x0;
    const float* p = in + (size_t)bc * 2304;
    float r0 = p[y0*48 + x0] * (1.f - wy) + p[y1*48 + x0] * wy;
    float r1 = p[y0*48 + x1] * (1.f - wy) + p[y1*48 + x1] * wy;
    out[idx] = r0 * (1.f - wx) + r1 * wx;
}

// ---------------- NCHW f32 -> NHWC packed bf16 (hi|lo<<16) transpose ----------------
template<int C>
__global__ void t_nhwc_kernel(const float* __restrict__ in, uint* __restrict__ out) {
    __shared__ float t[32][33];
    constexpr int PB = HW / 32;          // 288
    int blk = blockIdx.x;
    int p0 = (blk % PB) * 32;
    int c0 = ((blk / PB) % (C / 32)) * 32;
    int b = blk / (PB * (C / 32));
    int tp = threadIdx.x & 31, tg = threadIdx.x >> 5;   // tg 0..7
    #pragma unroll
    for (int r = 0; r < 4; r++) {
        int c = c0 + tg + r * 8;
        t[tg + r * 8][tp] = in[((size_t)b * C + c) * HW + p0 + tp];
    }
    __syncthreads();
    #pragma unroll
    for (int r = 0; r < 4; r++) {
        int p = p0 + tg + r * 8;
        float v = t[tp][tg + r * 8];
        ushort h = bfbits(v);
        ushort l = bfbits(v - bf2f(h));
        out[((size_t)b * HW + p) * C + c0 + tp] = packu(h, l);
    }
}

// ---------------- copy x1 into channels [128..256) of concat buffer ----------------
__global__ void copy_x1_kernel(const float* __restrict__ x1, float* __restrict__ xcat) {
    int idx = blockIdx.x * blockDim.x + threadIdx.x;
    const int total = Bn * OUTCH * HW;
    if (idx >= total) return;
    int b = idx / (OUTCH * HW);
    int r = idx % (OUTCH * HW);
    xcat[((size_t)b * INCH + OUTCH) * HW + r] = x1[idx];
}

// ---------------- offset conv (3x3, pad=1, COUT=18) fp32, channel-split partials -------
template<int CIN, int SPLIT>
__global__ void offconv_kernel(const float* __restrict__ in, const float* __restrict__ w,
                               float* __restrict__ part) {
    constexpr int CS = CIN / SPLIT;
    constexpr int BPS = Bn * HW / 256;   // 72
    int s = blockIdx.x / BPS;
    int p = (blockIdx.x % BPS) * 256 + threadIdx.x;
    int b = p / HW; int pin = p % HW;
    int i = pin / Ws, j = pin % Ws;
    const float* ib = in + ((size_t)b * CIN + s * CS) * HW;
    const float* wb = w + (size_t)s * CS * N9;
    float acc[18];
    #pragma unroll
    for (int o = 0; o < 18; o++) acc[o] = 0.f;
    for (int c = 0; c < CS; c++) {
        float v[9];
        #pragma unroll
        for (int n = 0; n < 9; n++) {
            int rr = i + n / 3 - 1, cc = j + n % 3 - 1;
            v[n] = (rr >= 0 && rr < Hs && cc >= 0 && cc < Ws) ? ib[(size_t)c * HW + rr * Ws + cc] : 0.f;
        }
        const float* wc = wb + (size_t)c * N9;
        #pragma unroll
        for (int o = 0; o < 18; o++) {
            #pragma unroll
            for (int n = 0; n < 9; n++) acc[o] += wc[(size_t)o * CIN * N9 + n] * v[n];
        }
    }
    #pragma unroll
    for (int o = 0; o < 18; o++)
        part[(((size_t)s * Bn + b) * 18 + o) * HW + pin] = acc[o];
}

template<int SPLIT>
__global__ void offreduce_kernel(const float* __restrict__ part, const float* __restrict__ bias,
                                 float* __restrict__ off) {
    int idx = blockIdx.x * blockDim.x + threadIdx.x;
    const int total = Bn * 18 * HW;
    if (idx >= total) return;
    int pin = idx % HW;
    int o = (idx / HW) % 18;
    int b = idx / (18 * HW);
    float a = bias[o];
    #pragma unroll
    for (int s = 0; s < SPLIT; s++) a += part[(((size_t)s * Bn + b) * 18 + o) * HW + pin];
    off[((size_t)b * 18 + o) * HW + pin] = a;
}

// ------ weight prep: [oc][c][3][3] fp32 -> bf16 hi[k/32][128][32] ++ lo; k = n*CIN + c ------
template<int CIN>
__global__ void wprep_big_kernel(const float* __restrict__ cw, ushort* __restrict__ wp) {
    int e = blockIdx.x * 256 + threadIdx.x;
    if (e >= CIN * 9 * 128) return;
    int kl = e & 31, oc = (e >> 5) & 127, k32 = e >> 12;
    int k = k32 * 32 + kl;
    int n = k / CIN, c = k & (CIN - 1);
    float v = cw[((size_t)oc * CIN + c) * 9 + n];
    ushort h = bfbits(v);
    wp[e] = h;
    wp[e + CIN * 9 * 128] = bfbits(v - bf2f(h));
}

// ---------------- sampling params: indices + bilinear weights ----------------
__global__ void mkparams_kernel(const float* __restrict__ off, int4* __restrict__ pidx,
                                float4* __restrict__ pw) {
    int e = blockIdx.x * blockDim.x + threadIdx.x;
    const int total = Bn * HW * N9;
    if (e >= total) return;
    int n = e % N9;
    int p = e / N9;
    int j = p % Ws;
    int i = (p / Ws) % Hs;
    int b = p / HW;
    float ox = off[((size_t)b * 18 + n) * HW + i * Ws + j];
    float oy = off[((size_t)b * 18 + 9 + n) * HW + i * Ws + j];
    float px = ox + (float)(n / 3 - 1) + (float)(i + 1);
    float py = oy + (float)(n % 3 - 1) + (float)(j + 1);
    float fx = floorf(px), fy = floorf(py);
    float x_lt = fminf(fmaxf(fx,       0.f), 95.f);
    float x_rb = fminf(fmaxf(fx + 1.f, 0.f), 95.f);
    float y_lt = fminf(fmaxf(fy,       0.f), 95.f);
    float y_rb = fminf(fmaxf(fy + 1.f, 0.f), 95.f);
    float pxc  = fminf(fmaxf(px, 0.f), 95.f);
    float pyc  = fminf(fmaxf(py, 0.f), 95.f);
    float g_lt = (1.f + (x_lt - pxc)) * (1.f + (y_lt - pyc));
    float g_rb = (1.f - (x_rb - pxc)) * (1.f - (y_rb - pyc));
    float g_lb = (1.f + (x_lt - pxc)) * (1.f - (y_rb - pyc));
    float g_rt = (1.f - (x_rb - pxc)) * (1.f + (y_lt - pyc));
    int ilt = (int)x_lt * Ws + (int)y_lt;
    int irb = (int)x_rb * Ws + (int)y_rb;
    int ilb = (int)x_lt * Ws + (int)y_rb;
    int irt = (int)x_rb * Ws + (int)y_lt;
    pidx[e] = make_int4(ilt, irb, ilb, irt);
    pw[e]   = make_float4(g_lt, g_rb, g_lb, g_rt);
}

// ---------------- MFMA GEMM, NHWC fill: 16 px x 128 oc per block, split-K x2 ----------------
// Input NHWC packed uint (hi|lo<<16). K-order: k = n*CIN + c; each 64-K step is one tap n.
// FILL LANES ARE CHANNEL-FASTEST: fc4 = tid&15, fpx = tid>>4 -> lanes 0..15 load 16
// consecutive uint4 of ONE pixel-neighbor = one 256B coalesced segment per 16-lane group.
// Software pipeline: bilinear(cur regs) -> issue next-step gather (same regs, WAR) ->
// barrier -> LDS write -> barrier -> MAC. Gather latency hides under write+barrier+MAC.
// 4 waves; wave w: oc slice [32w,32w+32). A = weights (m=oc), B = patch (n=px).
// D: col(lane&15)=px -> coalesced stores; row((lane>>4)*4+r)=oc.
template<int CIN, bool DEFORM, bool SPLIT3>
__global__ void mgemm_big_kernel(const uint* __restrict__ xT, const ushort* __restrict__ wp,
                                 const int4* __restrict__ pidx, const float4* __restrict__ pw,
                                 float* __restrict__ p0, float* __restrict__ p1) {
    constexpr int KS = CIN * 9 / 2;
    constexpr int NSTEP = KS / 64;
    constexpr int TILES = Bn * HW / 16;   // 1152
    __shared__ ushort Ah[16][80];         // [px][64k + pad] bf16 hi, col-swizzled
    __shared__ ushort Al[16][80];         // lo
    __shared__ int4  sidx[144];
    __shared__ float4 ssw[144];

    int tid = threadIdx.x;
    // XCD-aware swizzle: 2304 blocks, 8 XCDs, 288 contiguous per XCD
    int bid = blockIdx.x;
    int swz = (bid & 7) * 288 + (bid >> 3);
    int s = swz / TILES;
    int t = swz % TILES;
    int p0x = t * 16;
    int b = p0x / HW;
    int pin = p0x % HW;
    int irow = pin / Ws, j0 = pin % Ws;

    if constexpr (DEFORM) {
        if (tid < 144) {
            sidx[tid] = pidx[(size_t)p0x * N9 + tid];
            ssw[tid]  = pw[(size_t)p0x * N9 + tid];
        }
        __syncthreads();   // prologue gather below reads sidx
    }
    const uint* xbT = xT + (size_t)b * HW * CIN;
    const ushort* wlo = wp + (size_t)CIN * 9 * 128;
    int w = tid >> 6, lane = tid & 63;
    int lg = lane >> 4, l15 = lane & 15;
    int fpx = tid >> 4, fc4 = tid & 15;   // CHANNEL-FASTEST fill mapping

    f32x4 acc[2];
    acc[0] = (f32x4){0.f, 0.f, 0.f, 0.f};
    acc[1] = (f32x4){0.f, 0.f, 0.f, 0.f};
    int bswz = (l15 >> 2) << 3;           // read-side col swizzle (ushorts)
    int col = (fc4 * 4) ^ ((fpx >> 2) << 3);   // write-side swizzle (ushorts, 8B-aligned)

    uint4 qa, qb, qc, qd;
    // gather issue for step ks into qa..qd
    auto gload = [&](int ks) {
        int k0 = s * KS + ks * 64;
        int n = k0 / CIN;
        int cc = (k0 & (CIN - 1)) + fc4 * 4;
        if constexpr (DEFORM) {
            int4 i4 = sidx[fpx * 9 + n];
            qa = *(const uint4*)&xbT[(size_t)i4.x * CIN + cc];
            qb = *(const uint4*)&xbT[(size_t)i4.y * CIN + cc];
            qc = *(const uint4*)&xbT[(size_t)i4.z * CIN + cc];
            qd = *(const uint4*)&xbT[(size_t)i4.w * CIN + cc];
        } else {
            int n3 = n / 3;
            int rr = irow + n3 - 1, ccol = j0 + fpx + (n - 3 * n3) - 1;
            qa = make_uint4(0u, 0u, 0u, 0u);
            if (rr >= 0 && rr < Hs && ccol >= 0 && ccol < Ws)
                qa = *(const uint4*)&xbT[(size_t)(rr * Ws + ccol) * CIN + cc];
        }
    };
    gload(0);

    for (int ks = 0; ks < NSTEP; ks++) {
        int k0 = s * KS + ks * 64;
        // ---- consume regs -> h/l (bilinear for deform, bit-split for conv) ----
        ushort h[4], l[4];
        if constexpr (DEFORM) {
            int n = k0 / CIN;
            float4 w4 = ssw[fpx * 9 + n];
            uint ua[4] = {qa.x, qa.y, qa.z, qa.w};
            uint ub[4] = {qb.x, qb.y, qb.z, qb.w};
            uint uc[4] = {qc.x, qc.y, qc.z, qc.w};
            uint ud[4] = {qd.x, qd.y, qd.z, qd.w};
            #pragma unroll
            for (int j = 0; j < 4; j++) {
                float v = w4.x * (rchi(ua[j]) + rclo(ua[j]))
                        + w4.y * (rchi(ub[j]) + rclo(ub[j]))
                        + w4.z * (rchi(uc[j]) + rclo(uc[j]))
                        + w4.w * (rchi(ud[j]) + rclo(ud[j]));
                h[j] = bfbits(v);
                if constexpr (SPLIT3) l[j] = bfbits(v - bf2f(h[j]));
            }
        } else {
            uint ua[4] = {qa.x, qa.y, qa.z, qa.w};
            #pragma unroll
            for (int j = 0; j < 4; j++) {
                h[j] = (ushort)(ua[j] & 0xffffu);
                if constexpr (SPLIT3) l[j] = (ushort)(ua[j] >> 16);
            }
        }
        // ---- prefetch next step's gather (regs free after consume) ----
        if (ks + 1 < NSTEP) gload(ks + 1);
        __syncthreads();   // prior MAC done reading LDS
        uint2 wh; wh.x = packu(h[0], h[1]); wh.y = packu(h[2], h[3]);
        *(uint2*)&Ah[fpx][col] = wh;
        if constexpr (SPLIT3) {
            uint2 wl; wl.x = packu(l[0], l[1]); wl.y = packu(l[2], l[3]);
            *(uint2*)&Al[fpx][col] = wl;
        }
        __syncthreads();
        // ---- MAC: 2 K-halves; SPLIT3 -> ah*bh + ah*bl + al*bh ----
        #pragma unroll
        for (int kk = 0; kk < 2; kk++) {
            const ushort* wpk = wp + ((size_t)(k0 / 32 + kk) * 128) * 32;
            int bcol = (kk * 32 + lg * 8) ^ bswz;
            bf16x8 a0h = *(const bf16x8*)&wpk[(32 * w + l15) * 32 + lg * 8];
            bf16x8 a1h = *(const bf16x8*)&wpk[(32 * w + 16 + l15) * 32 + lg * 8];
            bf16x8 b0h = *(const bf16x8*)&Ah[l15][bcol];
            acc[0] = __builtin_amdgcn_mfma_f32_16x16x32_bf16(a0h, b0h, acc[0], 0, 0, 0);
            acc[1] = __builtin_amdgcn_mfma_f32_16x16x32_bf16(a1h, b0h, acc[1], 0, 0, 0);
            if constexpr (SPLIT3) {
                const ushort* wpl = wlo + ((size_t)(k0 / 32 + kk) * 128) * 32;
                bf16x8 a0l = *(const bf16x8*)&wpl[(32 * w + l15) * 32 + lg * 8];
                bf16x8 a1l = *(const bf16x8*)&wpl[(32 * w + 16 + l15) * 32 + lg * 8];
                bf16x8 b0l = *(const bf16x8*)&Al[l15][bcol];
                acc[0] = __builtin_amdgcn_mfma_f32_16x16x32_bf16(a0h, b0l, acc[0], 0, 0, 0);
                acc[0] = __builtin_amdgcn_mfma_f32_16x16x32_bf16(a0l, b0h, acc[0], 0, 0, 0);
                acc[1] = __builtin_amdgcn_mfma_f32_16x16x32_bf16(a1h, b0l, acc[1], 0, 0, 0);
                acc[1] = __builtin_amdgcn_mfma_f32_16x16x32_bf16(a1l, b0h, acc[1], 0, 0, 0);
            }
        }
    }
    float* pout = s ? p1 : p0;
    #pragma unroll
    for (int mf = 0; mf < 2; mf++) {
        int oc = 32 * w + 16 * mf + lg * 4;
        #pragma unroll
        for (int r = 0; r < 4; r++)
            pout[((size_t)b * OUTCH + oc + r) * HW + pin + l15] = acc[mf][r];
    }
}

// ---------------- combine split-K partials + bias + ReLU -> xcat[:, 0:128] ----------------
__global__ void combine_halve_kernel(const float* __restrict__ p0, const float* __restrict__ p1,
                                     const float* __restrict__ bias, float* __restrict__ xcat) {
    int idx = blockIdx.x * blockDim.x + threadIdx.x;
    const int total = Bn * OUTCH * HW;
    if (idx >= total) return;
    int b = idx / (OUTCH * HW);
    int o = (idx / HW) % OUTCH;
    int pin = idx % HW;
    float v = p0[idx] + p1[idx] + bias[o];
    xcat[((size_t)b * INCH + o) * HW + pin] = fmaxf(v, 0.f);
}

// ---------------- training-mode BN statistics over (p0+p1) ----------------
__global__ void bnstats_kernel(const float* __restrict__ p0, const float* __restrict__ p1,
                               float* __restrict__ mv) {
    int o = blockIdx.x;
    int tid = threadIdx.x;
    float s = 0.f, sq = 0.f;
    for (int k = tid; k < Bn * HW; k += 256) {
        int b = k / HW, p = k % HW;
        size_t idx = ((size_t)b * OUTCH + o) * HW + p;
        float v = p0[idx] + p1[idx];
        s += v; sq += v * v;
    }
    __shared__ float rs[256], rq[256];
    rs[tid] = s; rq[tid] = sq;
    __syncthreads();
    for (int st = 128; st > 0; st >>= 1) {
        if (tid < st) { rs[tid] += rs[tid + st]; rq[tid] += rq[tid + st]; }
        __syncthreads();
    }
    if (tid == 0) {
        float m = rs[0] / (float)(Bn * HW);
        mv[o] = m;
        mv[OUTCH + o] = rq[0] / (float)(Bn * HW) - m * m;
    }
}

// ---------------- BN apply + ReLU over (p0+p1) ----------------
__global__ void bnapply_kernel(const float* __restrict__ p0, const float* __restrict__ p1,
                               const float* __restrict__ mv,
                               const float* __restrict__ g, const float* __restrict__ be,
                               float* __restrict__ y) {
    int idx = blockIdx.x * blockDim.x + threadIdx.x;
    const int total = Bn * OUTCH * HW;
    if (idx >= total) return;
    int o = (idx / HW) % OUTCH;
    float m = mv[o], v = mv[OUTCH + o];
    float x = p0[idx] + p1[idx];
    float r = (x - m) / sqrtf(v + 1e-5f) * g[o] + be[o];
    y[idx] = fmaxf(r, 0.f);
}

extern "C" void kernel_launch(void* const* d_in, const int* in_sizes, int n_in,
                              void* d_out, int out_size, void* d_ws, size_t ws_size,
                              hipStream_t stream) {
    const float* x1   = (const float*)d_in[0];
    const float* x2   = (const float*)d_in[1];
    const float* chW  = (const float*)d_in[2];
    const float* chB  = (const float*)d_in[3];
    const float* p1W  = (const float*)d_in[4];
    const float* p1B  = (const float*)d_in[5];
    const float* c1W  = (const float*)d_in[6];
    const float* bn1g = (const float*)d_in[7];
    const float* bn1b = (const float*)d_in[8];
    const float* p2W  = (const float*)d_in[9];
    const float* p2B  = (const float*)d_in[10];
    const float* c2W  = (const float*)d_in[11];
    const float* bn2g = (const float*)d_in[12];
    const float* bn2b = (const float*)d_in[13];
    float* out = (float*)d_out;

    float* ws = (float*)d_ws;
    // Regions (floats): A=[0,4718592) B=[4718592,9437184) C=[9437184,11796480) D=[11796480,14155776)
    // Phase H: x2u@A -> x2uT@C∪D; cwThb@B[0..294912); mgemm: p0h@A[0), p1h@A[2359296);
    //          combine -> xcat@B; copy_x1 -> xcat@B
    // Stage 1: part@A, offb/pidx/pw/cwTb1@A tail; xcat@B -> xcatT@C∪D; p0d/p1d@B; y1@A[0)
    // Stage 2: part@B, offb/pidx/pw/cwTb2@B tail; y1@A -> y1T@C; p0d/p1d@A -> out
    float* x2u   = ws;
    uint*  x2uT  = (uint*)(ws + 9437184);
    ushort* cwThb = (ushort*)(ws + 4718592);
    float* p0h   = ws;
    float* p1h   = ws + 2359296;
    float* xcat  = ws + 4718592;

    float* part1 = ws;
    float* offb1 = ws + 2654208;
    int4*  pidx1 = (int4*)(ws + 2985984);
    float4* pw41 = (float4*)(ws + 3649536);
    ushort* cwTb1 = (ushort*)(ws + 4313088);
    uint*  xcatT = (uint*)(ws + 9437184);
    float* p0d1  = ws + 4718592;
    float* p1d1  = ws + 4718592 + 2359296;
    float* y1    = ws;

    float* part2 = ws + 4718592;
    float* offb2 = ws + 4718592 + 2654208;
    int4*  pidx2 = (int4*)(ws + 4718592 + 2985984);
    float4* pw42 = (float4*)(ws + 4718592 + 3649536);
    ushort* cwTb2 = (ushort*)(ws + 4718592 + 4313088);
    uint*  y1T   = (uint*)(ws + 9437184);
    float* p0d2  = ws;
    float* p1d2  = ws + 2359296;
    float* mv    = ws + 14155776;

    constexpr int BIG_GRID = 2 * Bn * HW / 16;          // 2304
    constexpr int T256_GRID = (HW/32) * (INCH/32) * Bn; // 4608
    constexpr int T128_GRID = (HW/32) * (OUTCH/32) * Bn;// 2304

    // ---- halve-channel conv ----
    up2_kernel<<<(Bn*INCH*HW + 255) / 256, 256, 0, stream>>>(x2, x2u);
    t_nhwc_kernel<INCH><<<T256_GRID, 256, 0, stream>>>(x2u, x2uT);
    wprep_big_kernel<INCH><<<(INCH*9*128 + 255) / 256, 256, 0, stream>>>(chW, cwThb);
    mgemm_big_kernel<INCH, false, true><<<BIG_GRID, 256, 0, stream>>>(x2uT, cwThb, nullptr, nullptr, p0h, p1h);
    combine_halve_kernel<<<(Bn*OUTCH*HW + 255) / 256, 256, 0, stream>>>(p0h, p1h, chB, xcat);
    copy_x1_kernel<<<(Bn*OUTCH*HW + 255) / 256, 256, 0, stream>>>(x1, xcat);

    // ---- stage 1 (offsets fp32; deform GEMM split-precision MFMA, NHWC coalesced fill) ----
    offconv_kernel<INCH, 8><<<8 * (Bn*HW/256), 256, 0, stream>>>(xcat, p1W, part1);
    offreduce_kernel<8><<<(Bn*18*HW + 255) / 256, 256, 0, stream>>>(part1, p1B, offb1);
    mkparams_kernel<<<(Bn*HW*N9 + 255) / 256, 256, 0, stream>>>(offb1, pidx1, pw41);
    wprep_big_kernel<INCH><<<(INCH*9*128 + 255) / 256, 256, 0, stream>>>(c1W, cwTb1);
    t_nhwc_kernel<INCH><<<T256_GRID, 256, 0, stream>>>(xcat, xcatT);
    mgemm_big_kernel<INCH, true, true><<<BIG_GRID, 256, 0, stream>>>(xcatT, cwTb1, pidx1, pw41, p0d1, p1d1);
    bnstats_kernel<<<OUTCH, 256, 0, stream>>>(p0d1, p1d1, mv);
    bnapply_kernel<<<(Bn*OUTCH*HW + 255) / 256, 256, 0, stream>>>(p0d1, p1d1, mv, bn1g, bn1b, y1);

    // ---- stage 2 (final output: plain bf16 MFMA) ----
    offconv_kernel<OUTCH, 8><<<8 * (Bn*HW/256), 256, 0, stream>>>(y1, p2W, part2);
    offreduce_kernel<8><<<(Bn*18*HW + 255) / 256, 256, 0, stream>>>(part2, p2B, offb2);
    mkparams_kernel<<<(Bn*HW*N9 + 255) / 256, 256, 0, stream>>>(offb2, pidx2, pw42);
    wprep_big_kernel<OUTCH><<<(OUTCH*9*128 + 255) / 256, 256, 0, stream>>>(c2W, cwTb2);
    t_nhwc_kernel<OUTCH><<<T128_GRID, 256, 0, stream>>>(y1, y1T);
    mgemm_big_kernel<OUTCH, true, false><<<BIG_GRID, 256, 0, stream>>>(y1T, cwTb2, pidx2, pw42, p0d2, p1d2);
    bnstats_kernel<<<OUTCH, 256, 0, stream>>>(p0d2, p1d2, mv);
    bnapply_kernel<<<(Bn*OUTCH*HW + 255) / 256, 256, 0, stream>>>(p0d2, p1d2, mv, bn2g, bn2b, out);
}

// Round 10
// 358.524 us; speedup vs baseline: 1.5128x; 1.2823x over previous
//
#include <hip/hip_runtime.h>
#include <hip/hip_bf16.h>

// Problem constants
#define Bn 2
#define INCH 256
#define OUTCH 128
#define Hs 96
#define Ws 96
#define HW (Hs*Ws)          // 9216
#define N9 9

typedef __attribute__((ext_vector_type(8))) short bf16x8;
typedef __attribute__((ext_vector_type(4))) float f32x4;

static __device__ inline ushort bfbits(float v) {
    __hip_bfloat16 h = __float2bfloat16(v);
    return *reinterpret_cast<ushort*>(&h);
}
static __device__ inline float bf2f(ushort u) {
    __hip_bfloat16 h = *reinterpret_cast<__hip_bfloat16*>(&u);
    return __bfloat162float(h);
}
static __device__ inline uint packu(ushort lo, ushort hi) {
    return (uint)lo | ((uint)hi << 16);
}
// NHWC packed value: uint = hi_bits | (lo_bits<<16); reconstruct f32 halves:
static __device__ inline float rchi(uint u) { return __uint_as_float(u << 16); }
static __device__ inline float rclo(uint u) { return __uint_as_float(u & 0xffff0000u); }

// -------- fused: bilinear up2 (align_corners) -> NHWC packed bf16 hi|lo --------
template<int C>
__global__ void up2_nhwc_kernel(const float* __restrict__ in, uint* __restrict__ out) {
    __shared__ float t[32][33];
    constexpr int PB = HW / 32;          // 288
    int blk = blockIdx.x;
    int p0 = (blk % PB) * 32;
    int c0 = ((blk / PB) % (C / 32)) * 32;
    int b = blk / (PB * (C / 32));
    int tp = threadIdx.x & 31, tg = threadIdx.x >> 5;
    int p = p0 + tp;
    int xo = p % Ws, yo = p / Ws;
    const float s = 47.0f / 95.0f;
    float yf = yo * s, xf = xo * s;
    int y0 = (int)floorf(yf); int y1 = min(y0 + 1, 47);
    int x0 = (int)floorf(xf); int x1 = min(x0 + 1, 47);
    float wy = yf - (float)y0, wx = xf - (float)x0;
    #pragma unroll
    for (int r = 0; r < 4; r++) {
        int c = c0 + tg + r * 8;
        const float* pp = in + ((size_t)b * C + c) * 2304;
        float r0 = pp[y0*48 + x0] * (1.f - wy) + pp[y1*48 + x0] * wy;
        float r1 = pp[y0*48 + x1] * (1.f - wy) + pp[y1*48 + x1] * wy;
        t[tg + r * 8][tp] = r0 * (1.f - wx) + r1 * wx;
    }
    __syncthreads();
    #pragma unroll
    for (int r = 0; r < 4; r++) {
        int po = p0 + tg + r * 8;
        float v = t[tp][tg + r * 8];
        ushort h = bfbits(v);
        ushort l = bfbits(v - bf2f(h));
        out[((size_t)b * HW + po) * C + c0 + tp] = packu(h, l);
    }
}

// -------- fused: combine split-K halve partials + bias + ReLU | copy x1 --------
// writes xcat (NCHW f32, for offconv) AND xcatT (NHWC packed, for deform gemm)
__global__ void combine_t_kernel(const float* __restrict__ ph0, const float* __restrict__ ph1,
                                 const float* __restrict__ x1, const float* __restrict__ bias,
                                 float* __restrict__ xcat, uint* __restrict__ xcatT) {
    __shared__ float t[32][33];
    constexpr int PB = HW / 32;
    int blk = blockIdx.x;
    int p0 = (blk % PB) * 32;
    int c0 = ((blk / PB) % (INCH / 32)) * 32;
    int b = blk / (PB * (INCH / 32));
    int tp = threadIdx.x & 31, tg = threadIdx.x >> 5;
    #pragma unroll
    for (int r = 0; r < 4; r++) {
        int c = c0 + tg + r * 8;
        float v;
        if (c < OUTCH) {
            size_t i = ((size_t)b * OUTCH + c) * HW + p0 + tp;
            v = fmaxf(ph0[i] + ph1[i] + bias[c], 0.f);
        } else {
            v = x1[((size_t)b * OUTCH + (c - OUTCH)) * HW + p0 + tp];
        }
        t[tg + r * 8][tp] = v;
        xcat[((size_t)b * INCH + c) * HW + p0 + tp] = v;
    }
    __syncthreads();
    #pragma unroll
    for (int r = 0; r < 4; r++) {
        int po = p0 + tg + r * 8;
        float v = t[tp][tg + r * 8];
        ushort h = bfbits(v);
        ushort l = bfbits(v - bf2f(h));
        xcatT[((size_t)b * HW + po) * INCH + c0 + tp] = packu(h, l);
    }
}

// -------- fused: BN apply + ReLU -> y1 (NCHW f32) AND y1T (NHWC packed) --------
__global__ void bnapply_t_kernel(const float* __restrict__ p0, const float* __restrict__ p1,
                                 const float* __restrict__ mv, const float* __restrict__ g,
                                 const float* __restrict__ be,
                                 float* __restrict__ y, uint* __restrict__ yT) {
    __shared__ float t[32][33];
    constexpr int PB = HW / 32;
    int blk = blockIdx.x;
    int p0x = (blk % PB) * 32;
    int c0 = ((blk / PB) % (OUTCH / 32)) * 32;
    int b = blk / (PB * (OUTCH / 32));
    int tp = threadIdx.x & 31, tg = threadIdx.x >> 5;
    #pragma unroll
    for (int r = 0; r < 4; r++) {
        int c = c0 + tg + r * 8;
        size_t i = ((size_t)b * OUTCH + c) * HW + p0x + tp;
        float m = mv[c], vv = mv[OUTCH + c];
        float x = p0[i] + p1[i];
        float rr = fmaxf((x - m) / sqrtf(vv + 1e-5f) * g[c] + be[c], 0.f);
        t[tg + r * 8][tp] = rr;
        y[i] = rr;
    }
    __syncthreads();
    #pragma unroll
    for (int r = 0; r < 4; r++) {
        int po = p0x + tg + r * 8;
        float v = t[tp][tg + r * 8];
        ushort h = bfbits(v);
        ushort l = bfbits(v - bf2f(h));
        yT[((size_t)b * HW + po) * OUTCH + c0 + tp] = packu(h, l);
    }
}

// ---------------- offset conv (3x3, pad=1, COUT=18) fp32, channel-split partials -------
template<int CIN, int SPLIT>
__global__ void offconv_kernel(const float* __restrict__ in, const float* __restrict__ w,
                               float* __restrict__ part) {
    constexpr int CS = CIN / SPLIT;
    constexpr int BPS = Bn * HW / 256;   // 72
    int s = blockIdx.x / BPS;
    int p = (blockIdx.x % BPS) * 256 + threadIdx.x;
    int b = p / HW; int pin = p % HW;
    int i = pin / Ws, j = pin % Ws;
    const float* ib = in + ((size_t)b * CIN + s * CS) * HW;
    const float* wb = w + (size_t)s * CS * N9;
    float acc[18];
    #pragma unroll
    for (int o = 0; o < 18; o++) acc[o] = 0.f;
    for (int c = 0; c < CS; c++) {
        float v[9];
        #pragma unroll
        for (int n = 0; n < 9; n++) {
            int rr = i + n / 3 - 1, cc = j + n % 3 - 1;
            v[n] = (rr >= 0 && rr < Hs && cc >= 0 && cc < Ws) ? ib[(size_t)c * HW + rr * Ws + cc] : 0.f;
        }
        const float* wc = wb + (size_t)c * N9;
        #pragma unroll
        for (int o = 0; o < 18; o++) {
            #pragma unroll
            for (int n = 0; n < 9; n++) acc[o] += wc[(size_t)o * CIN * N9 + n] * v[n];
        }
    }
    #pragma unroll
    for (int o = 0; o < 18; o++)
        part[(((size_t)s * Bn + b) * 18 + o) * HW + pin] = acc[o];
}

template<int SPLIT>
__global__ void offreduce_kernel(const float* __restrict__ part, const float* __restrict__ bias,
                                 float* __restrict__ off) {
    int idx = blockIdx.x * blockDim.x + threadIdx.x;
    const int total = Bn * 18 * HW;
    if (idx >= total) return;
    int pin = idx % HW;
    int o = (idx / HW) % 18;
    int b = idx / (18 * HW);
    float a = bias[o];
    #pragma unroll
    for (int s = 0; s < SPLIT; s++) a += part[(((size_t)s * Bn + b) * 18 + o) * HW + pin];
    off[((size_t)b * 18 + o) * HW + pin] = a;
}

// ------ weight prep: [oc][c][3][3] fp32 -> bf16 hi[k/32][128][32] ++ lo; k = n*CIN + c ------
template<int CIN>
__global__ void wprep_big_kernel(const float* __restrict__ cw, ushort* __restrict__ wp) {
    int e = blockIdx.x * 256 + threadIdx.x;
    if (e >= CIN * 9 * 128) return;
    int kl = e & 31, oc = (e >> 5) & 127, k32 = e >> 12;
    int k = k32 * 32 + kl;
    int n = k / CIN, c = k & (CIN - 1);
    float v = cw[((size_t)oc * CIN + c) * 9 + n];
    ushort h = bfbits(v);
    wp[e] = h;
    wp[e + CIN * 9 * 128] = bfbits(v - bf2f(h));
}

// ---------------- sampling params: indices + bilinear weights ----------------
__global__ void mkparams_kernel(const float* __restrict__ off, int4* __restrict__ pidx,
                                float4* __restrict__ pw) {
    int e = blockIdx.x * blockDim.x + threadIdx.x;
    const int total = Bn * HW * N9;
    if (e >= total) return;
    int n = e % N9;
    int p = e / N9;
    int j = p % Ws;
    int i = (p / Ws) % Hs;
    int b = p / HW;
    float ox = off[((size_t)b * 18 + n) * HW + i * Ws + j];
    float oy = off[((size_t)b * 18 + 9 + n) * HW + i * Ws + j];
    float px = ox + (float)(n / 3 - 1) + (float)(i + 1);
    float py = oy + (float)(n % 3 - 1) + (float)(j + 1);
    float fx = floorf(px), fy = floorf(py);
    float x_lt = fminf(fmaxf(fx,       0.f), 95.f);
    float x_rb = fminf(fmaxf(fx + 1.f, 0.f), 95.f);
    float y_lt = fminf(fmaxf(fy,       0.f), 95.f);
    float y_rb = fminf(fmaxf(fy + 1.f, 0.f), 95.f);
    float pxc  = fminf(fmaxf(px, 0.f), 95.f);
    float pyc  = fminf(fmaxf(py, 0.f), 95.f);
    float g_lt = (1.f + (x_lt - pxc)) * (1.f + (y_lt - pyc));
    float g_rb = (1.f - (x_rb - pxc)) * (1.f - (y_rb - pyc));
    float g_lb = (1.f + (x_lt - pxc)) * (1.f - (y_rb - pyc));
    float g_rt = (1.f - (x_rb - pxc)) * (1.f + (y_lt - pyc));
    int ilt = (int)x_lt * Ws + (int)y_lt;
    int irb = (int)x_rb * Ws + (int)y_rb;
    int ilb = (int)x_lt * Ws + (int)y_rb;
    int irt = (int)x_rb * Ws + (int)y_lt;
    pidx[e] = make_int4(ilt, irb, ilb, irt);
    pw[e]   = make_float4(g_lt, g_rb, g_lb, g_rt);
}

// ---------------- MFMA GEMM, NHWC fill: 32 px x 128 oc per block, split-K x2 ----------------
// Double-buffered LDS, ONE barrier per K-step. Channel-fastest fill lanes (fc4=tid&15):
// 16 lanes load 16 consecutive uint4 of one pixel-neighbor = 256B coalesced segment.
// Each thread fills 2 px (fpx, fpx+16). Register prefetch 1 step ahead.
// 4 waves; wave w: oc slice [32w,32w+32) x 32 px. A = weights (m=oc), B = patch (n=px).
// D: col(lane&15)=px -> coalesced stores; row((lane>>4)*4+r)=oc.
template<int CIN, bool DEFORM, bool SPLIT3>
__global__ void mgemm_big_kernel(const uint* __restrict__ xT, const ushort* __restrict__ wp,
                                 const int4* __restrict__ pidx, const float4* __restrict__ pw,
                                 float* __restrict__ p0, float* __restrict__ p1) {
    constexpr int KS = CIN * 9 / 2;
    constexpr int NSTEP = KS / 64;
    constexpr int PX = 32;
    constexpr int TILES = Bn * HW / PX;   // 576
    constexpr int CPX = 2 * TILES / 8;    // 144 blocks per XCD
    __shared__ ushort Ah[2][PX][80];      // [dbuf][px][64k + pad] bf16 hi, col-swizzled
    __shared__ ushort Al[2][PX][80];      // lo
    __shared__ int4  sidx[PX * N9];       // 288
    __shared__ float4 ssw[PX * N9];

    int tid = threadIdx.x;
    int bid = blockIdx.x;
    int swz = (bid & 7) * CPX + (bid >> 3);   // 1152 = 8*144, bijective
    int s = swz / TILES;
    int t = swz % TILES;
    int p0x = t * PX;
    int b = p0x / HW;
    int pin = p0x % HW;
    int irow = pin / Ws, j0 = pin % Ws;       // 32|96 -> tile within one row

    if constexpr (DEFORM) {
        for (int e = tid; e < PX * N9; e += 256) {
            sidx[e] = pidx[(size_t)p0x * N9 + e];
            ssw[e]  = pw[(size_t)p0x * N9 + e];
        }
        __syncthreads();
    }
    const uint* xbT = xT + (size_t)b * HW * CIN;
    const ushort* wlo = wp + (size_t)CIN * 9 * 128;
    int w = tid >> 6, lane = tid & 63;
    int lg = lane >> 4, l15 = lane & 15;
    int fpx = tid >> 4, fc4 = tid & 15;   // channel-fastest fill mapping

    f32x4 acc[2][2];
    #pragma unroll
    for (int mf = 0; mf < 2; mf++)
        #pragma unroll
        for (int nf = 0; nf < 2; nf++) acc[mf][nf] = (f32x4){0.f, 0.f, 0.f, 0.f};
    int bswz0 = (l15 >> 2) << 3;                       // read swizzle row l15
    int col0 = (fc4 * 4) ^ ((fpx >> 2) << 3);          // write swizzle row fpx
    int col1 = (fc4 * 4) ^ (((fpx + 16) >> 2) << 3);   // write swizzle row fpx+16

    uint4 qa0, qb0, qc0, qd0, qa1, qb1, qc1, qd1;
    auto gload = [&](int ks) {
        int k0 = s * KS + ks * 64;
        int n = k0 / CIN;
        int cc = (k0 & (CIN - 1)) + fc4 * 4;
        if constexpr (DEFORM) {
            int4 i4 = sidx[fpx * 9 + n];
            qa0 = *(const uint4*)&xbT[(size_t)i4.x * CIN + cc];
            qb0 = *(const uint4*)&xbT[(size_t)i4.y * CIN + cc];
            qc0 = *(const uint4*)&xbT[(size_t)i4.z * CIN + cc];
            qd0 = *(const uint4*)&xbT[(size_t)i4.w * CIN + cc];
            int4 j4 = sidx[(fpx + 16) * 9 + n];
            qa1 = *(const uint4*)&xbT[(size_t)j4.x * CIN + cc];
            qb1 = *(const uint4*)&xbT[(size_t)j4.y * CIN + cc];
            qc1 = *(const uint4*)&xbT[(size_t)j4.z * CIN + cc];
            qd1 = *(const uint4*)&xbT[(size_t)j4.w * CIN + cc];
        } else {
            int n3 = n / 3;
            int rr = irow + n3 - 1;
            int cl0 = j0 + fpx + (n - 3 * n3) - 1;
            qa0 = make_uint4(0u, 0u, 0u, 0u);
            qa1 = make_uint4(0u, 0u, 0u, 0u);
            if (rr >= 0 && rr < Hs) {
                if (cl0 >= 0 && cl0 < Ws)
                    qa0 = *(const uint4*)&xbT[(size_t)(rr * Ws + cl0) * CIN + cc];
                if (cl0 + 16 >= 0 && cl0 + 16 < Ws)
                    qa1 = *(const uint4*)&xbT[(size_t)(rr * Ws + cl0 + 16) * CIN + cc];
            }
        }
    };
    auto bil4 = [&](const uint4& A, const uint4& B, const uint4& C, const uint4& D,
                    const float4& w4, ushort* hh, ushort* ll) {
        const uint ua[4] = {A.x, A.y, A.z, A.w}, ub[4] = {B.x, B.y, B.z, B.w},
                   uc[4] = {C.x, C.y, C.z, C.w}, ud[4] = {D.x, D.y, D.z, D.w};
        #pragma unroll
        for (int j = 0; j < 4; j++) {
            float v = w4.x * (rchi(ua[j]) + rclo(ua[j])) + w4.y * (rchi(ub[j]) + rclo(ub[j]))
                    + w4.z * (rchi(uc[j]) + rclo(uc[j])) + w4.w * (rchi(ud[j]) + rclo(ud[j]));
            hh[j] = bfbits(v);
            if constexpr (SPLIT3) ll[j] = bfbits(v - bf2f(hh[j]));
        }
    };
    gload(0);

    for (int ks = 0; ks < NSTEP; ks++) {
        int k0 = s * KS + ks * 64;
        int cur = ks & 1;
        ushort h0[4], l0[4], h1[4], l1[4];
        if constexpr (DEFORM) {
            int n = k0 / CIN;
            float4 wA = ssw[fpx * 9 + n];
            float4 wB = ssw[(fpx + 16) * 9 + n];
            bil4(qa0, qb0, qc0, qd0, wA, h0, l0);
            bil4(qa1, qb1, qc1, qd1, wB, h1, l1);
        } else {
            const uint u0[4] = {qa0.x, qa0.y, qa0.z, qa0.w};
            const uint u1[4] = {qa1.x, qa1.y, qa1.z, qa1.w};
            #pragma unroll
            for (int j = 0; j < 4; j++) {
                h0[j] = (ushort)(u0[j] & 0xffffu);
                h1[j] = (ushort)(u1[j] & 0xffffu);
                if constexpr (SPLIT3) {
                    l0[j] = (ushort)(u0[j] >> 16);
                    l1[j] = (ushort)(u1[j] >> 16);
                }
            }
        }
        if (ks + 1 < NSTEP) gload(ks + 1);   // prefetch: latency hides under write+barrier+MAC
        {
            uint2 v0; v0.x = packu(h0[0], h0[1]); v0.y = packu(h0[2], h0[3]);
            uint2 v1; v1.x = packu(h1[0], h1[1]); v1.y = packu(h1[2], h1[3]);
            *(uint2*)&Ah[cur][fpx][col0] = v0;
            *(uint2*)&Ah[cur][fpx + 16][col1] = v1;
            if constexpr (SPLIT3) {
                uint2 w0; w0.x = packu(l0[0], l0[1]); w0.y = packu(l0[2], l0[3]);
                uint2 w1; w1.x = packu(l1[0], l1[1]); w1.y = packu(l1[2], l1[3]);
                *(uint2*)&Al[cur][fpx][col0] = w0;
                *(uint2*)&Al[cur][fpx + 16][col1] = w1;
            }
        }
        __syncthreads();   // single barrier: dbuf makes next iter's writes safe vs this MAC
        #pragma unroll
        for (int kk = 0; kk < 2; kk++) {
            const ushort* wpk = wp + ((size_t)(k0 / 32 + kk) * 128) * 32;
            int bc0 = (kk * 32 + lg * 8) ^ bswz0;
            int bc1 = bc0 ^ 32;                  // row fpx+16 swizzle = bswz0^32
            bf16x8 a0h = *(const bf16x8*)&wpk[(32 * w + l15) * 32 + lg * 8];
            bf16x8 a1h = *(const bf16x8*)&wpk[(32 * w + 16 + l15) * 32 + lg * 8];
            bf16x8 b0h = *(const bf16x8*)&Ah[cur][l15][bc0];
            bf16x8 b1h = *(const bf16x8*)&Ah[cur][16 + l15][bc1];
            acc[0][0] = __builtin_amdgcn_mfma_f32_16x16x32_bf16(a0h, b0h, acc[0][0], 0, 0, 0);
            acc[0][1] = __builtin_amdgcn_mfma_f32_16x16x32_bf16(a0h, b1h, acc[0][1], 0, 0, 0);
            acc[1][0] = __builtin_amdgcn_mfma_f32_16x16x32_bf16(a1h, b0h, acc[1][0], 0, 0, 0);
            acc[1][1] = __builtin_amdgcn_mfma_f32_16x16x32_bf16(a1h, b1h, acc[1][1], 0, 0, 0);
            if constexpr (SPLIT3) {
                const ushort* wpl = wlo + ((size_t)(k0 / 32 + kk) * 128) * 32;
                bf16x8 a0l = *(const bf16x8*)&wpl[(32 * w + l15) * 32 + lg * 8];
                bf16x8 a1l = *(const bf16x8*)&wpl[(32 * w + 16 + l15) * 32 + lg * 8];
                bf16x8 b0l = *(const bf16x8*)&Al[cur][l15][bc0];
                bf16x8 b1l = *(const bf16x8*)&Al[cur][16 + l15][bc1];
                acc[0][0] = __builtin_amdgcn_mfma_f32_16x16x32_bf16(a0h, b0l, acc[0][0], 0, 0, 0);
                acc[0][0] = __builtin_amdgcn_mfma_f32_16x16x32_bf16(a0l, b0h, acc[0][0], 0, 0, 0);
                acc[0][1] = __builtin_amdgcn_mfma_f32_16x16x32_bf16(a0h, b1l, acc[0][1], 0, 0, 0);
                acc[0][1] = __builtin_amdgcn_mfma_f32_16x16x32_bf16(a0l, b1h, acc[0][1], 0, 0, 0);
                acc[1][0] = __builtin_amdgcn_mfma_f32_16x16x32_bf16(a1h, b0l, acc[1][0], 0, 0, 0);
                acc[1][0] = __builtin_amdgcn_mfma_f32_16x16x32_bf16(a1l, b0h, acc[1][0], 0, 0, 0);
                acc[1][1] = __builtin_amdgcn_mfma_f32_16x16x32_bf16(a1h, b1l, acc[1][1], 0, 0, 0);
                acc[1][1] = __builtin_amdgcn_mfma_f32_16x16x32_bf16(a1l, b1h, acc[1][1], 0, 0, 0);
            }
        }
    }
    float* pout = s ? p1 : p0;
    #pragma unroll
    for (int mf = 0; mf < 2; mf++) {
        int oc = 32 * w + 16 * mf + lg * 4;
        #pragma unroll
        for (int nf = 0; nf < 2; nf++) {
            #pragma unroll
            for (int r = 0; r < 4; r++)
                pout[((size_t)b * OUTCH + oc + r) * HW + pin + nf * 16 + l15] = acc[mf][nf][r];
        }
    }
}

// ---------------- training-mode BN statistics over (p0+p1) ----------------
__global__ void bnstats_kernel(const float* __restrict__ p0, const float* __restrict__ p1,
                               float* __restrict__ mv) {
    int o = blockIdx.x;
    int tid = threadIdx.x;
    float s = 0.f, sq = 0.f;
    for (int k = tid; k < Bn * HW; k += 256) {
        int b = k / HW, p = k % HW;
        size_t idx = ((size_t)b * OUTCH + o) * HW + p;
        float v = p0[idx] + p1[idx];
        s += v; sq += v * v;
    }
    __shared__ float rs[256], rq[256];
    rs[tid] = s; rq[tid] = sq;
    __syncthreads();
    for (int st = 128; st > 0; st >>= 1) {
        if (tid < st) { rs[tid] += rs[tid + st]; rq[tid] += rq[tid + st]; }
        __syncthreads();
    }
    if (tid == 0) {
        float m = rs[0] / (float)(Bn * HW);
        mv[o] = m;
        mv[OUTCH + o] = rq[0] / (float)(Bn * HW) - m * m;
    }
}

// ---------------- BN apply + ReLU over (p0+p1) -> final out (NCHW only) ----------------
__global__ void bnapply_kernel(const float* __restrict__ p0, const float* __restrict__ p1,
                               const float* __restrict__ mv,
                               const float* __restrict__ g, const float* __restrict__ be,
                               float* __restrict__ y) {
    int idx = blockIdx.x * blockDim.x + threadIdx.x;
    const int total = Bn * OUTCH * HW;
    if (idx >= total) return;
    int o = (idx / HW) % OUTCH;
    float m = mv[o], v = mv[OUTCH + o];
    float x = p0[idx] + p1[idx];
    float r = (x - m) / sqrtf(v + 1e-5f) * g[o] + be[o];
    y[idx] = fmaxf(r, 0.f);
}

extern "C" void kernel_launch(void* const* d_in, const int* in_sizes, int n_in,
                              void* d_out, int out_size, void* d_ws, size_t ws_size,
                              hipStream_t stream) {
    const float* x1   = (const float*)d_in[0];
    const float* x2   = (const float*)d_in[1];
    const float* chW  = (const float*)d_in[2];
    const float* chB  = (const float*)d_in[3];
    const float* p1W  = (const float*)d_in[4];
    const float* p1B  = (const float*)d_in[5];
    const float* c1W  = (const float*)d_in[6];
    const float* bn1g = (const float*)d_in[7];
    const float* bn1b = (const float*)d_in[8];
    const float* p2W  = (const float*)d_in[9];
    const float* p2B  = (const float*)d_in[10];
    const float* c2W  = (const float*)d_in[11];
    const float* bn2g = (const float*)d_in[12];
    const float* bn2b = (const float*)d_in[13];
    float* out = (float*)d_out;

    float* ws = (float*)d_ws;
    // Regions (floats): A=[0,4718592) B=[4718592,9437184) C=[9437184,11796480) D=[11796480,14155776)
    // Phase H: x2uT@C∪D; cwThb@B[0); p0h/p1h@A; combine_t -> xcat@B + xcatT@C∪D (x2uT dead)
    // Stage 1: part1@A[0), offb1/pidx1/pw41/cwTb1@A tail; p0d1/p1d1@B (xcat dead after offconv);
    //          bnapply_t -> y1@A[0) + y1T@C (xcatT dead)
    // Stage 2: part2@B[0), offb2/pidx2/pw42/cwTb2@B tail; p0d2/p1d2@A (y1 dead after offconv2) -> out
    uint*  x2uT  = (uint*)(ws + 9437184);
    ushort* cwThb = (ushort*)(ws + 4718592);
    float* p0h   = ws;
    float* p1h   = ws + 2359296;
    float* xcat  = ws + 4718592;
    uint*  xcatT = (uint*)(ws + 9437184);

    float* part1 = ws;
    float* offb1 = ws + 2654208;
    int4*  pidx1 = (int4*)(ws + 2985984);
    float4* pw41 = (float4*)(ws + 3649536);
    ushort* cwTb1 = (ushort*)(ws + 4313088);
    float* p0d1  = ws + 4718592;
    float* p1d1  = ws + 4718592 + 2359296;
    float* y1    = ws;
    uint*  y1T   = (uint*)(ws + 9437184);

    float* part2 = ws + 4718592;
    float* offb2 = ws + 4718592 + 2654208;
    int4*  pidx2 = (int4*)(ws + 4718592 + 2985984);
    float4* pw42 = (float4*)(ws + 4718592 + 3649536);
    ushort* cwTb2 = (ushort*)(ws + 4718592 + 4313088);
    float* p0d2  = ws;
    float* p1d2  = ws + 2359296;
    float* mv    = ws + 14155776;

    constexpr int BIG_GRID = 2 * Bn * HW / 32;          // 1152
    constexpr int UP_GRID  = (HW/32) * (INCH/32) * Bn;  // 4608
    constexpr int CT_GRID  = (HW/32) * (INCH/32) * Bn;  // 4608
    constexpr int BT_GRID  = (HW/32) * (OUTCH/32) * Bn; // 2304

    // ---- halve-channel conv ----
    up2_nhwc_kernel<INCH><<<UP_GRID, 256, 0, stream>>>(x2, x2uT);
    wprep_big_kernel<INCH><<<(INCH*9*128 + 255) / 256, 256, 0, stream>>>(chW, cwThb);
    mgemm_big_kernel<INCH, false, true><<<BIG_GRID, 256, 0, stream>>>(x2uT, cwThb, nullptr, nullptr, p0h, p1h);
    combine_t_kernel<<<CT_GRID, 256, 0, stream>>>(p0h, p1h, x1, chB, xcat, xcatT);

    // ---- stage 1 (offsets fp32; deform GEMM split-precision MFMA, NHWC coalesced fill) ----
    offconv_kernel<INCH, 8><<<8 * (Bn*HW/256), 256, 0, stream>>>(xcat, p1W, part1);
    offreduce_kernel<8><<<(Bn*18*HW + 255) / 256, 256, 0, stream>>>(part1, p1B, offb1);
    mkparams_kernel<<<(Bn*HW*N9 + 255) / 256, 256, 0, stream>>>(offb1, pidx1, pw41);
    wprep_big_kernel<INCH><<<(INCH*9*128 + 255) / 256, 256, 0, stream>>>(c1W, cwTb1);
    mgemm_big_kernel<INCH, true, true><<<BIG_GRID, 256, 0, stream>>>(xcatT, cwTb1, pidx1, pw41, p0d1, p1d1);
    bnstats_kernel<<<OUTCH, 256, 0, stream>>>(p0d1, p1d1, mv);
    bnapply_t_kernel<<<BT_GRID, 256, 0, stream>>>(p0d1, p1d1, mv, bn1g, bn1b, y1, y1T);

    // ---- stage 2 (final output: plain bf16 MFMA) ----
    offconv_kernel<OUTCH, 8><<<8 * (Bn*HW/256), 256, 0, stream>>>(y1, p2W, part2);
    offreduce_kernel<8><<<(Bn*18*HW + 255) / 256, 256, 0, stream>>>(part2, p2B, offb2);
    mkparams_kernel<<<(Bn*HW*N9 + 255) / 256, 256, 0, stream>>>(offb2, pidx2, pw42);
    wprep_big_kernel<OUTCH><<<(OUTCH*9*128 + 255) / 256, 256, 0, stream>>>(c2W, cwTb2);
    mgemm_big_kernel<OUTCH, true, false><<<BIG_GRID, 256, 0, stream>>>(y1T, cwTb2, pidx2, pw42, p0d2, p1d2);
    bnstats_kernel<<<OUTCH, 256, 0, stream>>>(p0d2, p1d2, mv);
    bnapply_kernel<<<(Bn*OUTCH*HW + 255) / 256, 256, 0, stream>>>(p0d2, p1d2, mv, bn2g, bn2b, out);
}

// Round 12
// 355.177 us; speedup vs baseline: 1.5271x; 1.0094x over previous
//
#include <hip/hip_runtime.h>
#include <hip/hip_bf16.h>

// Problem constants
#define Bn 2
#define INCH 256
#define OUTCH 128
#define Hs 96
#define Ws 96
#define HW (Hs*Ws)          // 9216
#define N9 9

typedef __attribute__((ext_vector_type(8))) short bf16x8;
typedef __attribute__((ext_vector_type(4))) float f32x4;

static __device__ inline ushort bfbits(float v) {
    __hip_bfloat16 h = __float2bfloat16(v);
    return *reinterpret_cast<ushort*>(&h);
}
static __device__ inline float bf2f(ushort u) {
    __hip_bfloat16 h = *reinterpret_cast<__hip_bfloat16*>(&u);
    return __bfloat162float(h);
}
static __device__ inline uint packu(ushort lo, ushort hi) {
    return (uint)lo | ((uint)hi << 16);
}
// NHWC packed value: uint = hi_bits | (lo_bits<<16); reconstruct f32 halves:
static __device__ inline float rchi(uint u) { return __uint_as_float(u << 16); }
static __device__ inline float rclo(uint u) { return __uint_as_float(u & 0xffff0000u); }

// sampling params for (b, n, pixel pp) — EXACT copy of mkparams math
static __device__ inline void mkpar(const float* __restrict__ off, int b, int n, int pp,
                                    int4& i4, float4& w4) {
    int i = pp / Ws, j = pp % Ws;
    float ox = off[((size_t)(b * 18 + n)) * HW + pp];
    float oy = off[((size_t)(b * 18 + 9 + n)) * HW + pp];
    float px = ox + (float)(n / 3 - 1) + (float)(i + 1);
    float py = oy + (float)(n % 3 - 1) + (float)(j + 1);
    float fx = floorf(px), fy = floorf(py);
    float x_lt = fminf(fmaxf(fx,       0.f), 95.f);
    float x_rb = fminf(fmaxf(fx + 1.f, 0.f), 95.f);
    float y_lt = fminf(fmaxf(fy,       0.f), 95.f);
    float y_rb = fminf(fmaxf(fy + 1.f, 0.f), 95.f);
    float pxc  = fminf(fmaxf(px, 0.f), 95.f);
    float pyc  = fminf(fmaxf(py, 0.f), 95.f);
    w4.x = (1.f + (x_lt - pxc)) * (1.f + (y_lt - pyc));   // g_lt
    w4.y = (1.f - (x_rb - pxc)) * (1.f - (y_rb - pyc));   // g_rb
    w4.z = (1.f + (x_lt - pxc)) * (1.f - (y_rb - pyc));   // g_lb
    w4.w = (1.f - (x_rb - pxc)) * (1.f + (y_lt - pyc));   // g_rt
    i4.x = (int)x_lt * Ws + (int)y_lt;
    i4.y = (int)x_rb * Ws + (int)y_rb;
    i4.z = (int)x_lt * Ws + (int)y_rb;
    i4.w = (int)x_rb * Ws + (int)y_lt;
}

// -------- fused: bilinear up2 (align_corners) -> NHWC packed bf16 hi|lo --------
template<int C>
__global__ void up2_nhwc_kernel(const float* __restrict__ in, uint* __restrict__ out) {
    __shared__ float t[32][33];
    constexpr int PB = HW / 32;          // 288
    int blk = blockIdx.x;
    int p0 = (blk % PB) * 32;
    int c0 = ((blk / PB) % (C / 32)) * 32;
    int b = blk / (PB * (C / 32));
    int tp = threadIdx.x & 31, tg = threadIdx.x >> 5;
    int p = p0 + tp;
    int xo = p % Ws, yo = p / Ws;
    const float s = 47.0f / 95.0f;
    float yf = yo * s, xf = xo * s;
    int y0 = (int)floorf(yf); int y1 = min(y0 + 1, 47);
    int x0 = (int)floorf(xf); int x1 = min(x0 + 1, 47);
    float wy = yf - (float)y0, wx = xf - (float)x0;
    #pragma unroll
    for (int r = 0; r < 4; r++) {
        int c = c0 + tg + r * 8;
        const float* pp = in + ((size_t)b * C + c) * 2304;
        float r0 = pp[y0*48 + x0] * (1.f - wy) + pp[y1*48 + x0] * wy;
        float r1 = pp[y0*48 + x1] * (1.f - wy) + pp[y1*48 + x1] * wy;
        t[tg + r * 8][tp] = r0 * (1.f - wx) + r1 * wx;
    }
    __syncthreads();
    #pragma unroll
    for (int r = 0; r < 4; r++) {
        int po = p0 + tg + r * 8;
        float v = t[tp][tg + r * 8];
        ushort h = bfbits(v);
        ushort l = bfbits(v - bf2f(h));
        out[((size_t)b * HW + po) * C + c0 + tp] = packu(h, l);
    }
}

// -------- fused: combine split-K halve partials + bias + ReLU | copy x1 --------
__global__ void combine_t_kernel(const float* __restrict__ ph0, const float* __restrict__ ph1,
                                 const float* __restrict__ x1, const float* __restrict__ bias,
                                 float* __restrict__ xcat, uint* __restrict__ xcatT) {
    __shared__ float t[32][33];
    constexpr int PB = HW / 32;
    int blk = blockIdx.x;
    int p0 = (blk % PB) * 32;
    int c0 = ((blk / PB) % (INCH / 32)) * 32;
    int b = blk / (PB * (INCH / 32));
    int tp = threadIdx.x & 31, tg = threadIdx.x >> 5;
    #pragma unroll
    for (int r = 0; r < 4; r++) {
        int c = c0 + tg + r * 8;
        float v;
        if (c < OUTCH) {
            size_t i = ((size_t)b * OUTCH + c) * HW + p0 + tp;
            v = fmaxf(ph0[i] + ph1[i] + bias[c], 0.f);
        } else {
            v = x1[((size_t)b * OUTCH + (c - OUTCH)) * HW + p0 + tp];
        }
        t[tg + r * 8][tp] = v;
        xcat[((size_t)b * INCH + c) * HW + p0 + tp] = v;
    }
    __syncthreads();
    #pragma unroll
    for (int r = 0; r < 4; r++) {
        int po = p0 + tg + r * 8;
        float v = t[tp][tg + r * 8];
        ushort h = bfbits(v);
        ushort l = bfbits(v - bf2f(h));
        xcatT[((size_t)b * HW + po) * INCH + c0 + tp] = packu(h, l);
    }
}

// -------- fused: BN apply + ReLU over 2 partials -> y1 (NCHW f32) AND y1T (NHWC) --------
__global__ void bnapply_t_kernel(const float* __restrict__ p0, const float* __restrict__ p1,
                                 const float* __restrict__ mv, const float* __restrict__ g,
                                 const float* __restrict__ be,
                                 float* __restrict__ y, uint* __restrict__ yT) {
    __shared__ float t[32][33];
    constexpr int PB = HW / 32;
    int blk = blockIdx.x;
    int p0x = (blk % PB) * 32;
    int c0 = ((blk / PB) % (OUTCH / 32)) * 32;
    int b = blk / (PB * (OUTCH / 32));
    int tp = threadIdx.x & 31, tg = threadIdx.x >> 5;
    #pragma unroll
    for (int r = 0; r < 4; r++) {
        int c = c0 + tg + r * 8;
        size_t i = ((size_t)b * OUTCH + c) * HW + p0x + tp;
        float m = mv[c], vv = mv[OUTCH + c];
        float x = p0[i] + p1[i];
        float rr = fmaxf((x - m) / sqrtf(vv + 1e-5f) * g[c] + be[c], 0.f);
        t[tg + r * 8][tp] = rr;
        y[i] = rr;
    }
    __syncthreads();
    #pragma unroll
    for (int r = 0; r < 4; r++) {
        int po = p0x + tg + r * 8;
        float v = t[tp][tg + r * 8];
        ushort h = bfbits(v);
        ushort l = bfbits(v - bf2f(h));
        yT[((size_t)b * HW + po) * OUTCH + c0 + tp] = packu(h, l);
    }
}

// ---------------- offset conv (3x3, pad=1, COUT=18) fp32, channel-split partials -------
template<int CIN, int SPLIT>
__global__ void offconv_kernel(const float* __restrict__ in, const float* __restrict__ w,
                               float* __restrict__ part) {
    constexpr int CS = CIN / SPLIT;
    constexpr int BPS = Bn * HW / 256;   // 72
    int s = blockIdx.x / BPS;
    int p = (blockIdx.x % BPS) * 256 + threadIdx.x;
    int b = p / HW; int pin = p % HW;
    int i = pin / Ws, j = pin % Ws;
    const float* ib = in + ((size_t)b * CIN + s * CS) * HW;
    const float* wb = w + (size_t)s * CS * N9;
    float acc[18];
    #pragma unroll
    for (int o = 0; o < 18; o++) acc[o] = 0.f;
    for (int c = 0; c < CS; c++) {
        float v[9];
        #pragma unroll
        for (int n = 0; n < 9; n++) {
            int rr = i + n / 3 - 1, cc = j + n % 3 - 1;
            v[n] = (rr >= 0 && rr < Hs && cc >= 0 && cc < Ws) ? ib[(size_t)c * HW + rr * Ws + cc] : 0.f;
        }
        const float* wc = wb + (size_t)c * N9;
        #pragma unroll
        for (int o = 0; o < 18; o++) {
            #pragma unroll
            for (int n = 0; n < 9; n++) acc[o] += wc[(size_t)o * CIN * N9 + n] * v[n];
        }
    }
    #pragma unroll
    for (int o = 0; o < 18; o++)
        part[(((size_t)s * Bn + b) * 18 + o) * HW + pin] = acc[o];
}

template<int SPLIT>
__global__ void offreduce_kernel(const float* __restrict__ part, const float* __restrict__ bias,
                                 float* __restrict__ off) {
    int idx = blockIdx.x * blockDim.x + threadIdx.x;
    const int total = Bn * 18 * HW;
    if (idx >= total) return;
    int pin = idx % HW;
    int o = (idx / HW) % 18;
    int b = idx / (18 * HW);
    float a = bias[o];
    #pragma unroll
    for (int s = 0; s < SPLIT; s++) a += part[(((size_t)s * Bn + b) * 18 + o) * HW + pin];
    off[((size_t)b * 18 + o) * HW + pin] = a;
}

// ------ weight prep: [oc][c][3][3] fp32 -> bf16 hi[k/32][128][32] ++ lo; k = n*CIN + c ------
template<int CIN>
__global__ void wprep_big_kernel(const float* __restrict__ cw, ushort* __restrict__ wp) {
    int e = blockIdx.x * 256 + threadIdx.x;
    if (e >= CIN * 9 * 128) return;
    int kl = e & 31, oc = (e >> 5) & 127, k32 = e >> 12;
    int k = k32 * 32 + kl;
    int n = k / CIN, c = k & (CIN - 1);
    float v = cw[((size_t)oc * CIN + c) * 9 + n];
    ushort h = bfbits(v);
    wp[e] = h;
    wp[e + CIN * 9 * 128] = bfbits(v - bf2f(h));
}

// ---------------- sampling params: indices + bilinear weights (stage 1) ----------------
__global__ void mkparams_kernel(const float* __restrict__ off, int4* __restrict__ pidx,
                                float4* __restrict__ pw) {
    int e = blockIdx.x * blockDim.x + threadIdx.x;
    const int total = Bn * HW * N9;
    if (e >= total) return;
    int n = e % N9;
    int p = e / N9;
    int j = p % Ws;
    int i = (p / Ws) % Hs;
    int b = p / HW;
    float ox = off[((size_t)b * 18 + n) * HW + i * Ws + j];
    float oy = off[((size_t)b * 18 + 9 + n) * HW + i * Ws + j];
    float px = ox + (float)(n / 3 - 1) + (float)(i + 1);
    float py = oy + (float)(n % 3 - 1) + (float)(j + 1);
    float fx = floorf(px), fy = floorf(py);
    float x_lt = fminf(fmaxf(fx,       0.f), 95.f);
    float x_rb = fminf(fmaxf(fx + 1.f, 0.f), 95.f);
    float y_lt = fminf(fmaxf(fy,       0.f), 95.f);
    float y_rb = fminf(fmaxf(fy + 1.f, 0.f), 95.f);
    float pxc  = fminf(fmaxf(px, 0.f), 95.f);
    float pyc  = fminf(fmaxf(py, 0.f), 95.f);
    float g_lt = (1.f + (x_lt - pxc)) * (1.f + (y_lt - pyc));
    float g_rb = (1.f - (x_rb - pxc)) * (1.f - (y_rb - pyc));
    float g_lb = (1.f + (x_lt - pxc)) * (1.f - (y_rb - pyc));
    float g_rt = (1.f - (x_rb - pxc)) * (1.f + (y_lt - pyc));
    int ilt = (int)x_lt * Ws + (int)y_lt;
    int irb = (int)x_rb * Ws + (int)y_rb;
    int ilb = (int)x_lt * Ws + (int)y_rb;
    int irt = (int)x_rb * Ws + (int)y_lt;
    pidx[e] = make_int4(ilt, irb, ilb, irt);
    pw[e]   = make_float4(g_lt, g_rb, g_lb, g_rt);
}

// ---------------- MFMA GEMM (round-9 exact): 32px x 128oc, split-K x2, pidx/pw ----------
template<int CIN, bool DEFORM, bool SPLIT3>
__global__ void mgemm_big_kernel(const uint* __restrict__ xT, const ushort* __restrict__ wp,
                                 const int4* __restrict__ pidx, const float4* __restrict__ pw,
                                 float* __restrict__ p0, float* __restrict__ p1) {
    constexpr int KS = CIN * 9 / 2;
    constexpr int NSTEP = KS / 64;
    constexpr int PX = 32;
    constexpr int TILES = Bn * HW / PX;   // 576
    constexpr int CPX = 2 * TILES / 8;    // 144
    __shared__ ushort Ah[2][PX][80];
    __shared__ ushort Al[2][PX][80];
    __shared__ int4  sidx[PX * N9];
    __shared__ float4 ssw[PX * N9];

    int tid = threadIdx.x;
    int bid = blockIdx.x;
    int swz = (bid & 7) * CPX + (bid >> 3);
    int s = swz / TILES;
    int t = swz % TILES;
    int p0x = t * PX;
    int b = p0x / HW;
    int pin = p0x % HW;
    int irow = pin / Ws, j0 = pin % Ws;

    if constexpr (DEFORM) {
        for (int e = tid; e < PX * N9; e += 256) {
            sidx[e] = pidx[(size_t)p0x * N9 + e];
            ssw[e]  = pw[(size_t)p0x * N9 + e];
        }
        __syncthreads();
    }
    const uint* xbT = xT + (size_t)b * HW * CIN;
    const ushort* wlo = wp + (size_t)CIN * 9 * 128;
    int w = tid >> 6, lane = tid & 63;
    int lg = lane >> 4, l15 = lane & 15;
    int fpx = tid >> 4, fc4 = tid & 15;

    f32x4 acc[2][2];
    #pragma unroll
    for (int mf = 0; mf < 2; mf++)
        #pragma unroll
        for (int nf = 0; nf < 2; nf++) acc[mf][nf] = (f32x4){0.f, 0.f, 0.f, 0.f};
    int bswz0 = (l15 >> 2) << 3;
    int col0 = (fc4 * 4) ^ ((fpx >> 2) << 3);
    int col1 = (fc4 * 4) ^ (((fpx + 16) >> 2) << 3);

    uint4 qa0, qb0, qc0, qd0, qa1, qb1, qc1, qd1;
    auto gload = [&](int ks) {
        int k0 = s * KS + ks * 64;
        int n = k0 / CIN;
        int cc = (k0 & (CIN - 1)) + fc4 * 4;
        if constexpr (DEFORM) {
            int4 i4 = sidx[fpx * 9 + n];
            qa0 = *(const uint4*)&xbT[(size_t)i4.x * CIN + cc];
            qb0 = *(const uint4*)&xbT[(size_t)i4.y * CIN + cc];
            qc0 = *(const uint4*)&xbT[(size_t)i4.z * CIN + cc];
            qd0 = *(const uint4*)&xbT[(size_t)i4.w * CIN + cc];
            int4 j4 = sidx[(fpx + 16) * 9 + n];
            qa1 = *(const uint4*)&xbT[(size_t)j4.x * CIN + cc];
            qb1 = *(const uint4*)&xbT[(size_t)j4.y * CIN + cc];
            qc1 = *(const uint4*)&xbT[(size_t)j4.z * CIN + cc];
            qd1 = *(const uint4*)&xbT[(size_t)j4.w * CIN + cc];
        } else {
            int n3 = n / 3;
            int rr = irow + n3 - 1;
            int cl0 = j0 + fpx + (n - 3 * n3) - 1;
            qa0 = make_uint4(0u, 0u, 0u, 0u);
            qa1 = make_uint4(0u, 0u, 0u, 0u);
            if (rr >= 0 && rr < Hs) {
                if (cl0 >= 0 && cl0 < Ws)
                    qa0 = *(const uint4*)&xbT[(size_t)(rr * Ws + cl0) * CIN + cc];
                if (cl0 + 16 >= 0 && cl0 + 16 < Ws)
                    qa1 = *(const uint4*)&xbT[(size_t)(rr * Ws + cl0 + 16) * CIN + cc];
            }
        }
    };
    auto bil4 = [&](const uint4& A, const uint4& B, const uint4& C, const uint4& D,
                    const float4& w4, ushort* hh, ushort* ll) {
        const uint ua[4] = {A.x, A.y, A.z, A.w}, ub[4] = {B.x, B.y, B.z, B.w},
                   uc[4] = {C.x, C.y, C.z, C.w}, ud[4] = {D.x, D.y, D.z, D.w};
        #pragma unroll
        for (int j = 0; j < 4; j++) {
            float v = w4.x * (rchi(ua[j]) + rclo(ua[j])) + w4.y * (rchi(ub[j]) + rclo(ub[j]))
                    + w4.z * (rchi(uc[j]) + rclo(uc[j])) + w4.w * (rchi(ud[j]) + rclo(ud[j]));
            hh[j] = bfbits(v);
            if constexpr (SPLIT3) ll[j] = bfbits(v - bf2f(hh[j]));
        }
    };
    gload(0);

    for (int ks = 0; ks < NSTEP; ks++) {
        int k0 = s * KS + ks * 64;
        int cur = ks & 1;
        ushort h0[4], l0[4], h1[4], l1[4];
        if constexpr (DEFORM) {
            int n = k0 / CIN;
            float4 wA = ssw[fpx * 9 + n];
            float4 wB = ssw[(fpx + 16) * 9 + n];
            bil4(qa0, qb0, qc0, qd0, wA, h0, l0);
            bil4(qa1, qb1, qc1, qd1, wB, h1, l1);
        } else {
            const uint u0[4] = {qa0.x, qa0.y, qa0.z, qa0.w};
            const uint u1[4] = {qa1.x, qa1.y, qa1.z, qa1.w};
            #pragma unroll
            for (int j = 0; j < 4; j++) {
                h0[j] = (ushort)(u0[j] & 0xffffu);
                h1[j] = (ushort)(u1[j] & 0xffffu);
                if constexpr (SPLIT3) {
                    l0[j] = (ushort)(u0[j] >> 16);
                    l1[j] = (ushort)(u1[j] >> 16);
                }
            }
        }
        if (ks + 1 < NSTEP) gload(ks + 1);
        {
            uint2 v0; v0.x = packu(h0[0], h0[1]); v0.y = packu(h0[2], h0[3]);
            uint2 v1; v1.x = packu(h1[0], h1[1]); v1.y = packu(h1[2], h1[3]);
            *(uint2*)&Ah[cur][fpx][col0] = v0;
            *(uint2*)&Ah[cur][fpx + 16][col1] = v1;
            if constexpr (SPLIT3) {
                uint2 w0; w0.x = packu(l0[0], l0[1]); w0.y = packu(l0[2], l0[3]);
                uint2 w1; w1.x = packu(l1[0], l1[1]); w1.y = packu(l1[2], l1[3]);
                *(uint2*)&Al[cur][fpx][col0] = w0;
                *(uint2*)&Al[cur][fpx + 16][col1] = w1;
            }
        }
        __syncthreads();
        #pragma unroll
        for (int kk = 0; kk < 2; kk++) {
            const ushort* wpk = wp + ((size_t)(k0 / 32 + kk) * 128) * 32;
            int bc0 = (kk * 32 + lg * 8) ^ bswz0;
            int bc1 = bc0 ^ 32;
            bf16x8 a0h = *(const bf16x8*)&wpk[(32 * w + l15) * 32 + lg * 8];
            bf16x8 a1h = *(const bf16x8*)&wpk[(32 * w + 16 + l15) * 32 + lg * 8];
            bf16x8 b0h = *(const bf16x8*)&Ah[cur][l15][bc0];
            bf16x8 b1h = *(const bf16x8*)&Ah[cur][16 + l15][bc1];
            acc[0][0] = __builtin_amdgcn_mfma_f32_16x16x32_bf16(a0h, b0h, acc[0][0], 0, 0, 0);
            acc[0][1] = __builtin_amdgcn_mfma_f32_16x16x32_bf16(a0h, b1h, acc[0][1], 0, 0, 0);
            acc[1][0] = __builtin_amdgcn_mfma_f32_16x16x32_bf16(a1h, b0h, acc[1][0], 0, 0, 0);
            acc[1][1] = __builtin_amdgcn_mfma_f32_16x16x32_bf16(a1h, b1h, acc[1][1], 0, 0, 0);
            if constexpr (SPLIT3) {
                const ushort* wpl = wlo + ((size_t)(k0 / 32 + kk) * 128) * 32;
                bf16x8 a0l = *(const bf16x8*)&wpl[(32 * w + l15) * 32 + lg * 8];
                bf16x8 a1l = *(const bf16x8*)&wpl[(32 * w + 16 + l15) * 32 + lg * 8];
                bf16x8 b0l = *(const bf16x8*)&Al[cur][l15][bc0];
                bf16x8 b1l = *(const bf16x8*)&Al[cur][16 + l15][bc1];
                acc[0][0] = __builtin_amdgcn_mfma_f32_16x16x32_bf16(a0h, b0l, acc[0][0], 0, 0, 0);
                acc[0][0] = __builtin_amdgcn_mfma_f32_16x16x32_bf16(a0l, b0h, acc[0][0], 0, 0, 0);
                acc[0][1] = __builtin_amdgcn_mfma_f32_16x16x32_bf16(a0h, b1l, acc[0][1], 0, 0, 0);
                acc[0][1] = __builtin_amdgcn_mfma_f32_16x16x32_bf16(a0l, b1h, acc[0][1], 0, 0, 0);
                acc[1][0] = __builtin_amdgcn_mfma_f32_16x16x32_bf16(a1h, b0l, acc[1][0], 0, 0, 0);
                acc[1][0] = __builtin_amdgcn_mfma_f32_16x16x32_bf16(a1l, b0h, acc[1][0], 0, 0, 0);
                acc[1][1] = __builtin_amdgcn_mfma_f32_16x16x32_bf16(a1h, b1l, acc[1][1], 0, 0, 0);
                acc[1][1] = __builtin_amdgcn_mfma_f32_16x16x32_bf16(a1l, b1h, acc[1][1], 0, 0, 0);
            }
        }
    }
    float* pout = s ? p1 : p0;
    #pragma unroll
    for (int mf = 0; mf < 2; mf++) {
        int oc = 32 * w + 16 * mf + lg * 4;
        #pragma unroll
        for (int nf = 0; nf < 2; nf++) {
            #pragma unroll
            for (int r = 0; r < 4; r++)
                pout[((size_t)b * OUTCH + oc + r) * HW + pin + nf * 16 + l15] = acc[mf][nf][r];
        }
    }
}

// ---- stage-2 only: deform GEMM, split-K x3, INLINE mkpar, plain bf16, LDS 10.2KB ----
template<int CIN>
__global__ void mgemm_d3_kernel(const uint* __restrict__ xT, const ushort* __restrict__ wp,
                                const float* __restrict__ offb,
                                float* __restrict__ q0, float* __restrict__ q1,
                                float* __restrict__ q2) {
    constexpr int KS = CIN * 3;           // CIN*9/3
    constexpr int NSTEP = KS / 64;
    constexpr int PX = 32;
    constexpr int TILES = Bn * HW / PX;   // 576
    constexpr int CPX = 3 * TILES / 8;    // 216
    __shared__ ushort Ah[2][PX][80];

    int tid = threadIdx.x;
    int bid = blockIdx.x;
    int swz = (bid & 7) * CPX + (bid >> 3);   // bijective, grid = 1728
    int s = swz / TILES;
    int t = swz % TILES;
    int p0x = t * PX;
    int b = p0x / HW;
    int pin = p0x % HW;

    const uint* xbT = xT + (size_t)b * HW * CIN;
    int w = tid >> 6, lane = tid & 63;
    int lg = lane >> 4, l15 = lane & 15;
    int fpx = tid >> 4, fc4 = tid & 15;
    int pp0 = pin + fpx, pp1 = pin + fpx + 16;

    f32x4 acc[2][2];
    #pragma unroll
    for (int mf = 0; mf < 2; mf++)
        #pragma unroll
        for (int nf = 0; nf < 2; nf++) acc[mf][nf] = (f32x4){0.f, 0.f, 0.f, 0.f};
    int bswz0 = (l15 >> 2) << 3;
    int col0 = (fc4 * 4) ^ ((fpx >> 2) << 3);
    int col1 = (fc4 * 4) ^ (((fpx + 16) >> 2) << 3);

    int4 ia0, ia1; float4 wa0, wa1;
    int ncur = (s * KS) / CIN;            // 3*s
    mkpar(offb, b, ncur, pp0, ia0, wa0);
    mkpar(offb, b, ncur, pp1, ia1, wa1);

    uint4 qa0, qb0, qc0, qd0, qa1, qb1, qc1, qd1;
    auto gload = [&](int ks) {
        int k0 = s * KS + ks * 64;
        int cc = (k0 & (CIN - 1)) + fc4 * 4;
        qa0 = *(const uint4*)&xbT[(size_t)ia0.x * CIN + cc];
        qb0 = *(const uint4*)&xbT[(size_t)ia0.y * CIN + cc];
        qc0 = *(const uint4*)&xbT[(size_t)ia0.z * CIN + cc];
        qd0 = *(const uint4*)&xbT[(size_t)ia0.w * CIN + cc];
        qa1 = *(const uint4*)&xbT[(size_t)ia1.x * CIN + cc];
        qb1 = *(const uint4*)&xbT[(size_t)ia1.y * CIN + cc];
        qc1 = *(const uint4*)&xbT[(size_t)ia1.z * CIN + cc];
        qd1 = *(const uint4*)&xbT[(size_t)ia1.w * CIN + cc];
    };
    auto bil4h = [&](const uint4& A, const uint4& B, const uint4& C, const uint4& D,
                     const float4& w4, ushort* hh) {
        const uint ua[4] = {A.x, A.y, A.z, A.w}, ub[4] = {B.x, B.y, B.z, B.w},
                   uc[4] = {C.x, C.y, C.z, C.w}, ud[4] = {D.x, D.y, D.z, D.w};
        #pragma unroll
        for (int j = 0; j < 4; j++) {
            float v = w4.x * (rchi(ua[j]) + rclo(ua[j])) + w4.y * (rchi(ub[j]) + rclo(ub[j]))
                    + w4.z * (rchi(uc[j]) + rclo(uc[j])) + w4.w * (rchi(ud[j]) + rclo(ud[j]));
            hh[j] = bfbits(v);
        }
    };
    gload(0);

    for (int ks = 0; ks < NSTEP; ks++) {
        int k0 = s * KS + ks * 64;
        int cur = ks & 1;
        ushort h0[4], h1[4];
        bil4h(qa0, qb0, qc0, qd0, wa0, h0);
        bil4h(qa1, qb1, qc1, qd1, wa1, h1);
        if (ks + 1 < NSTEP) {
            int nn = (k0 + 64) / CIN;     // wave-uniform tap change
            if (nn != ncur) {
                ncur = nn;
                mkpar(offb, b, ncur, pp0, ia0, wa0);
                mkpar(offb, b, ncur, pp1, ia1, wa1);
            }
            gload(ks + 1);
        }
        {
            uint2 v0; v0.x = packu(h0[0], h0[1]); v0.y = packu(h0[2], h0[3]);
            uint2 v1; v1.x = packu(h1[0], h1[1]); v1.y = packu(h1[2], h1[3]);
            *(uint2*)&Ah[cur][fpx][col0] = v0;
            *(uint2*)&Ah[cur][fpx + 16][col1] = v1;
        }
        __syncthreads();
        #pragma unroll
        for (int kk = 0; kk < 2; kk++) {
            const ushort* wpk = wp + ((size_t)(k0 / 32 + kk) * 128) * 32;
            int bc0 = (kk * 32 + lg * 8) ^ bswz0;
            int bc1 = bc0 ^ 32;
            bf16x8 a0h = *(const bf16x8*)&wpk[(32 * w + l15) * 32 + lg * 8];
            bf16x8 a1h = *(const bf16x8*)&wpk[(32 * w + 16 + l15) * 32 + lg * 8];
            bf16x8 b0h = *(const bf16x8*)&Ah[cur][l15][bc0];
            bf16x8 b1h = *(const bf16x8*)&Ah[cur][16 + l15][bc1];
            acc[0][0] = __builtin_amdgcn_mfma_f32_16x16x32_bf16(a0h, b0h, acc[0][0], 0, 0, 0);
            acc[0][1] = __builtin_amdgcn_mfma_f32_16x16x32_bf16(a0h, b1h, acc[0][1], 0, 0, 0);
            acc[1][0] = __builtin_amdgcn_mfma_f32_16x16x32_bf16(a1h, b0h, acc[1][0], 0, 0, 0);
            acc[1][1] = __builtin_amdgcn_mfma_f32_16x16x32_bf16(a1h, b1h, acc[1][1], 0, 0, 0);
        }
    }
    float* pout = (s == 0) ? q0 : (s == 1) ? q1 : q2;
    #pragma unroll
    for (int mf = 0; mf < 2; mf++) {
        int oc = 32 * w + 16 * mf + lg * 4;
        #pragma unroll
        for (int nf = 0; nf < 2; nf++) {
            #pragma unroll
            for (int r = 0; r < 4; r++)
                pout[((size_t)b * OUTCH + oc + r) * HW + pin + nf * 16 + l15] = acc[mf][nf][r];
        }
    }
}

// ---------------- BN stats / apply: 2-partial (stage 1) and 3-partial (stage 2) --------
__global__ void bnstats_kernel(const float* __restrict__ p0, const float* __restrict__ p1,
                               float* __restrict__ mv) {
    int o = blockIdx.x;
    int tid = threadIdx.x;
    float s = 0.f, sq = 0.f;
    for (int k = tid; k < Bn * HW; k += 256) {
        int b = k / HW, p = k % HW;
        size_t idx = ((size_t)b * OUTCH + o) * HW + p;
        float v = p0[idx] + p1[idx];
        s += v; sq += v * v;
    }
    __shared__ float rs[256], rq[256];
    rs[tid] = s; rq[tid] = sq;
    __syncthreads();
    for (int st = 128; st > 0; st >>= 1) {
        if (tid < st) { rs[tid] += rs[tid + st]; rq[tid] += rq[tid + st]; }
        __syncthreads();
    }
    if (tid == 0) {
        float m = rs[0] / (float)(Bn * HW);
        mv[o] = m;
        mv[OUTCH + o] = rq[0] / (float)(Bn * HW) - m * m;
    }
}

__global__ void bnstats3_kernel(const float* __restrict__ q0, const float* __restrict__ q1,
                                const float* __restrict__ q2, float* __restrict__ mv) {
    int o = blockIdx.x;
    int tid = threadIdx.x;
    float s = 0.f, sq = 0.f;
    for (int k = tid; k < Bn * HW; k += 256) {
        int b = k / HW, p = k % HW;
        size_t idx = ((size_t)b * OUTCH + o) * HW + p;
        float v = q0[idx] + q1[idx] + q2[idx];
        s += v; sq += v * v;
    }
    __shared__ float rs[256], rq[256];
    rs[tid] = s; rq[tid] = sq;
    __syncthreads();
    for (int st = 128; st > 0; st >>= 1) {
        if (tid < st) { rs[tid] += rs[tid + st]; rq[tid] += rq[tid + st]; }
        __syncthreads();
    }
    if (tid == 0) {
        float m = rs[0] / (float)(Bn * HW);
        mv[o] = m;
        mv[OUTCH + o] = rq[0] / (float)(Bn * HW) - m * m;
    }
}

__global__ void bnapply3_kernel(const float* __restrict__ q0, const float* __restrict__ q1,
                                const float* __restrict__ q2, const float* __restrict__ mv,
                                const float* __restrict__ g, const float* __restrict__ be,
                                float* __restrict__ y) {
    int idx = blockIdx.x * blockDim.x + threadIdx.x;
    const int total = Bn * OUTCH * HW;
    if (idx >= total) return;
    int o = (idx / HW) % OUTCH;
    float m = mv[o], v = mv[OUTCH + o];
    float x = q0[idx] + q1[idx] + q2[idx];
    float r = (x - m) / sqrtf(v + 1e-5f) * g[o] + be[o];
    y[idx] = fmaxf(r, 0.f);
}

extern "C" void kernel_launch(void* const* d_in, const int* in_sizes, int n_in,
                              void* d_out, int out_size, void* d_ws, size_t ws_size,
                              hipStream_t stream) {
    const float* x1   = (const float*)d_in[0];
    const float* x2   = (const float*)d_in[1];
    const float* chW  = (const float*)d_in[2];
    const float* chB  = (const float*)d_in[3];
    const float* p1W  = (const float*)d_in[4];
    const float* p1B  = (const float*)d_in[5];
    const float* c1W  = (const float*)d_in[6];
    const float* bn1g = (const float*)d_in[7];
    const float* bn1b = (const float*)d_in[8];
    const float* p2W  = (const float*)d_in[9];
    const float* p2B  = (const float*)d_in[10];
    const float* c2W  = (const float*)d_in[11];
    const float* bn2g = (const float*)d_in[12];
    const float* bn2b = (const float*)d_in[13];
    float* out = (float*)d_out;

    float* ws = (float*)d_ws;
    // Round-9 layout (floats). P = 2,359,296.
    // Phase H: x2uT@[4P,6P); cwThb@[2P,+294912); qh0@[0,P), qh1@[P,2P);
    //          combine_t -> xcat@[2P,4P) + xcatT@[4P,6P)
    // Stage 1 (round-9 exact): part1@[0,2654208), offb1@[2654208,2985984),
    //   pidx1@[2985984,3649536), pw41@[3649536,4313088), cwTb1@[4313088,+147456);
    //   mgemm1: p0d1@[2P,3P), p1d1@[3P,4P); bnapply_t -> y1@[0,P) + y1T@[4P,5P)
    // Stage 2 (new d3): part2@[2P,2P+2654208), offb2@[2P+2654208,2P+2985984),
    //   cwTb2@[2P+4313088,+147456); mgemm_d3: q0d2@[0,P), q1d2@[P,2P), q2d2@[2P,3P)
    //   (part2 dead; offb2/cwTb2 live above 3P? no: offb2 ends 2P+2985984=7704576 > 3P=7077888!)
    //   -> q2d2 instead @[5P,6P) (y1T needs only [4P,5P); xcatT dead).
    constexpr size_t P = 2359296;
    uint*  x2uT  = (uint*)(ws + 4 * P);
    ushort* cwThb = (ushort*)(ws + 2 * P);
    float* qh0   = ws;
    float* qh1   = ws + P;
    float* xcat  = ws + 2 * P;
    uint*  xcatT = (uint*)(ws + 4 * P);

    float* part1 = ws;
    float* offb1 = ws + 2654208;
    int4*  pidx1 = (int4*)(ws + 2985984);
    float4* pw41 = (float4*)(ws + 3649536);
    ushort* cwTb1 = (ushort*)(ws + 4313088);
    float* p0d1  = ws + 2 * P;
    float* p1d1  = ws + 3 * P;
    float* y1    = ws;
    uint*  y1T   = (uint*)(ws + 4 * P);

    float* part2 = ws + 2 * P;
    float* offb2 = ws + 2 * P + 2654208;
    ushort* cwTb2 = (ushort*)(ws + 2 * P + 4313088);
    float* q0d2  = ws;
    float* q1d2  = ws + P;
    float* q2d2  = ws + 5 * P;
    float* mv    = ws + 6 * P;

    constexpr int TILES = Bn * HW / 32;                 // 576
    constexpr int BIG_GRID = 2 * TILES;                 // 1152
    constexpr int D3_GRID  = 3 * TILES;                 // 1728
    constexpr int UP_GRID  = (HW/32) * (INCH/32) * Bn;  // 4608
    constexpr int CT_GRID  = (HW/32) * (INCH/32) * Bn;  // 4608
    constexpr int BT_GRID  = (HW/32) * (OUTCH/32) * Bn; // 2304

    // ---- halve-channel conv (round-9 exact) ----
    up2_nhwc_kernel<INCH><<<UP_GRID, 256, 0, stream>>>(x2, x2uT);
    wprep_big_kernel<INCH><<<(INCH*9*128 + 255) / 256, 256, 0, stream>>>(chW, cwThb);
    mgemm_big_kernel<INCH, false, true><<<BIG_GRID, 256, 0, stream>>>(x2uT, cwThb, nullptr, nullptr, qh0, qh1);
    combine_t_kernel<<<CT_GRID, 256, 0, stream>>>(qh0, qh1, x1, chB, xcat, xcatT);

    // ---- stage 1 (round-9 exact: precomputed pidx/pw, split-K x2, split-precision) ----
    offconv_kernel<INCH, 8><<<8 * (Bn*HW/256), 256, 0, stream>>>(xcat, p1W, part1);
    offreduce_kernel<8><<<(Bn*18*HW + 255) / 256, 256, 0, stream>>>(part1, p1B, offb1);
    mkparams_kernel<<<(Bn*HW*N9 + 255) / 256, 256, 0, stream>>>(offb1, pidx1, pw41);
    wprep_big_kernel<INCH><<<(INCH*9*128 + 255) / 256, 256, 0, stream>>>(c1W, cwTb1);
    mgemm_big_kernel<INCH, true, true><<<BIG_GRID, 256, 0, stream>>>(xcatT, cwTb1, pidx1, pw41, p0d1, p1d1);
    bnstats_kernel<<<OUTCH, 256, 0, stream>>>(p0d1, p1d1, mv);
    bnapply_t_kernel<<<BT_GRID, 256, 0, stream>>>(p0d1, p1d1, mv, bn1g, bn1b, y1, y1T);

    // ---- stage 2 (NEW: inline mkpar, split-K x3, plain bf16, 10.2KB LDS) ----
    offconv_kernel<OUTCH, 8><<<8 * (Bn*HW/256), 256, 0, stream>>>(y1, p2W, part2);
    offreduce_kernel<8><<<(Bn*18*HW + 255) / 256, 256, 0, stream>>>(part2, p2B, offb2);
    wprep_big_kernel<OUTCH><<<(OUTCH*9*128 + 255) / 256, 256, 0, stream>>>(c2W, cwTb2);
    mgemm_d3_kernel<OUTCH><<<D3_GRID, 256, 0, stream>>>(y1T, cwTb2, offb2, q0d2, q1d2, q2d2);
    bnstats3_kernel<<<OUTCH, 256, 0, stream>>>(q0d2, q1d2, q2d2, mv);
    bnapply3_kernel<<<(Bn*OUTCH*HW + 255) / 256, 256, 0, stream>>>(q0d2, q1d2, q2d2, mv, bn2g, bn2b, out);
}